// Round 1
// baseline (805.079 us; speedup 1.0000x reference)
//
#include <hip/hip_runtime.h>
#include <hip/hip_bf16.h>

// GAT, 2 layers. N=50000, F=128, H=4, C=32, E=1.6M (+N self-loops).
// Strategy: fp32 GEMM (LDS-tiled) -> per-head logits -> CSR-by-dst build
// -> gather-based single-pass softmax aggregation (no output atomics).

#define FDIM 128
#define NHEAD 4

// ---------------- GEMM: C[M][128] = A[M][128] @ B[128][128], fp32 ----------
__global__ __launch_bounds__(256) void gemm128(const float* __restrict__ A,
                                               const float* __restrict__ B,
                                               float* __restrict__ C, int M) {
    __shared__ float As[128 * 64];    // [k][m] (transposed)  32 KB
    __shared__ float Bs[128 * 128];   // [k][n]               64 KB
    const int tid = threadIdx.x;
    const int bm = blockIdx.x * 64;

    // stage B (whole 128x128), coalesced float4
    #pragma unroll
    for (int i = 0; i < 16; i++) {
        int idx = tid + i * 256;
        ((float4*)Bs)[idx] = ((const float4*)B)[idx];
    }
    // stage A tile transposed: 64 rows x 128 cols
    #pragma unroll
    for (int i = 0; i < 8; i++) {
        int idx = tid + i * 256;      // float4 index
        int row = idx >> 5;           // 0..63
        int k4  = idx & 31;           // 0..31
        int grow = bm + row;
        float4 v = make_float4(0.f, 0.f, 0.f, 0.f);
        if (grow < M) v = ((const float4*)A)[grow * 32 + k4];
        As[(k4 * 4 + 0) * 64 + row] = v.x;
        As[(k4 * 4 + 1) * 64 + row] = v.y;
        As[(k4 * 4 + 2) * 64 + row] = v.z;
        As[(k4 * 4 + 3) * 64 + row] = v.w;
    }
    __syncthreads();

    const int mg = tid >> 5;   // 0..7  -> m0 = mg*8
    const int ng = tid & 31;   // n0 = ng*4
    float acc[8][4] = {};
    const float* Ap = &As[mg * 8];
    const float* Bp = &Bs[ng * 4];
    #pragma unroll 4
    for (int k = 0; k < 128; k++) {
        float4 a0 = *(const float4*)(Ap + k * 64);
        float4 a1 = *(const float4*)(Ap + k * 64 + 4);
        float4 b  = *(const float4*)(Bp + k * 128);
        float av[8] = {a0.x, a0.y, a0.z, a0.w, a1.x, a1.y, a1.z, a1.w};
        float bv[4] = {b.x, b.y, b.z, b.w};
        #pragma unroll
        for (int i = 0; i < 8; i++)
            #pragma unroll
            for (int j = 0; j < 4; j++)
                acc[i][j] += av[i] * bv[j];
    }
    #pragma unroll
    for (int i = 0; i < 8; i++) {
        int grow = bm + mg * 8 + i;
        if (grow < M) {
            float4 v = make_float4(acc[i][0], acc[i][1], acc[i][2], acc[i][3]);
            ((float4*)C)[grow * 32 + ng] = v;
        }
    }
}

// --------------- per-node attention logits: a_s[n][h], a_d[n][h] -----------
__global__ __launch_bounds__(128) void attn_logits(const float* __restrict__ h,
                                                   const float* __restrict__ att_s,
                                                   const float* __restrict__ att_d,
                                                   float* __restrict__ a_s,
                                                   float* __restrict__ a_d, int n) {
    int nid = blockIdx.x;
    int c = threadIdx.x;             // 0..127, head = c>>5
    float v = h[nid * FDIM + c];
    float ps = v * att_s[c];
    float pd = v * att_d[c];
    #pragma unroll
    for (int s = 16; s > 0; s >>= 1) {
        ps += __shfl_xor(ps, s, 64);
        pd += __shfl_xor(pd, s, 64);
    }
    if ((c & 31) == 0) {
        int hd = c >> 5;
        a_s[nid * NHEAD + hd] = ps;
        a_d[nid * NHEAD + hd] = pd;
    }
}

// ------------------------------ CSR build ---------------------------------
__global__ void hist_kernel(const int* __restrict__ dst, int E, int* __restrict__ deg) {
    int i = blockIdx.x * blockDim.x + threadIdx.x;
    if (i < E) atomicAdd(&deg[dst[i]], 1);
}

// single-block exclusive scan (wave shfl + cross-wave LDS), writes row_ptr & cursor
__global__ __launch_bounds__(1024) void scan_kernel(const int* __restrict__ deg,
                                                    int* __restrict__ row_ptr,
                                                    int* __restrict__ cursor, int n) {
    __shared__ int ws[16];
    __shared__ int wo[17];
    const int tid = threadIdx.x;
    const int lane = tid & 63, wid = tid >> 6;
    int offset = 0;
    for (int base = 0; base < n; base += 1024) {
        int i = base + tid;
        int v = (i < n) ? deg[i] : 0;
        int incl = v;
        #pragma unroll
        for (int s = 1; s < 64; s <<= 1) {
            int t = __shfl_up(incl, s, 64);
            if (lane >= s) incl += t;
        }
        if (lane == 63) ws[wid] = incl;
        __syncthreads();
        if (wid == 0 && lane < 16) {
            int wincl = ws[lane];
            #pragma unroll
            for (int s = 1; s < 16; s <<= 1) {
                int t = __shfl_up(wincl, s, 64);
                if (lane >= s) wincl += t;
            }
            wo[lane + 1] = wincl;
            if (lane == 0) wo[0] = 0;
        }
        __syncthreads();
        int excl = offset + wo[wid] + incl - v;
        if (i < n) { row_ptr[i] = excl; cursor[i] = excl; }
        offset += wo[16];
        __syncthreads();   // protect ws/wo reuse next chunk
    }
    if (tid == 0) row_ptr[n] = offset;
}

__global__ void scatter_kernel(const int* __restrict__ src, const int* __restrict__ dst,
                               int E, int* __restrict__ cursor, int* __restrict__ col) {
    int i = blockIdx.x * blockDim.x + threadIdx.x;
    if (i < E) {
        int pos = atomicAdd(&cursor[dst[i]], 1);
        col[pos] = src[i];
    }
}

// ------------- gather aggregation: softmax-weighted sum per dst ------------
// one block (128 thr) per dst node; thread = feature channel; head = c>>5.
// num/den accumulated in one pass (softmax is linear in unnormalized exp).
__global__ __launch_bounds__(128) void aggregate(const float* __restrict__ h,
                                                 const float* __restrict__ a_s,
                                                 const float* __restrict__ a_d,
                                                 const int* __restrict__ row_ptr,
                                                 const int* __restrict__ col,
                                                 const float* __restrict__ bias,
                                                 float* __restrict__ out,
                                                 float* __restrict__ out2,
                                                 int n, int do_relu) {
    const int nid = blockIdx.x;
    const int c = threadIdx.x;
    const int hd = c >> 5;
    const float ad = a_d[nid * NHEAD + hd];

    // self loop (src = dst)
    float e = a_s[nid * NHEAD + hd] + ad;
    e = (e > 0.f) ? e : 0.2f * e;
    float w = __expf(e);
    float den = w;
    float num = w * h[nid * FDIM + c];

    const int beg = row_ptr[nid], end = row_ptr[nid + 1];
    for (int j = beg; j < end; j++) {
        int s = col[j];
        float e2 = a_s[s * NHEAD + hd] + ad;
        e2 = (e2 > 0.f) ? e2 : 0.2f * e2;
        float w2 = __expf(e2);
        den += w2;
        num += w2 * h[s * FDIM + c];
    }
    float o = num / den + bias[c];
    if (do_relu) o = fmaxf(o, 0.f);
    out[nid * FDIM + c] = o;
    if (out2) out2[nid * FDIM + c] = o;
}

// ------------------------------- launcher ----------------------------------
extern "C" void kernel_launch(void* const* d_in, const int* in_sizes, int n_in,
                              void* d_out, int out_size, void* d_ws, size_t ws_size,
                              hipStream_t stream) {
    const float* x        = (const float*)d_in[0];
    const int*   edge     = (const int*)d_in[1];
    const float* W1       = (const float*)d_in[2];
    const float* att_s1   = (const float*)d_in[3];
    const float* att_d1   = (const float*)d_in[4];
    const float* b1       = (const float*)d_in[5];
    const float* W2       = (const float*)d_in[6];
    const float* att_s2   = (const float*)d_in[7];
    const float* att_d2   = (const float*)d_in[8];
    const float* b2       = (const float*)d_in[9];
    float* out = (float*)d_out;

    const int N = in_sizes[0] / FDIM;         // 50000
    const int E = in_sizes[1] / 2;            // 1600000
    const int* src = edge;
    const int* dst = edge + E;

    // workspace carve-up (all 256B aligned)
    char* w = (char*)d_ws;
    size_t off = 0;
    auto alloc = [&](size_t bytes) { void* p = w + off; off = (off + bytes + 255) & ~(size_t)255; return p; };
    int*   deg     = (int*)alloc((size_t)N * 4);
    int*   row_ptr = (int*)alloc((size_t)(N + 1) * 4);
    int*   cursor  = (int*)alloc((size_t)N * 4);
    int*   col     = (int*)alloc((size_t)E * 4);
    float* h1      = (float*)alloc((size_t)N * FDIM * 4);   // also reused as h2
    float* hx      = (float*)alloc((size_t)N * FDIM * 4);
    float* as1     = (float*)alloc((size_t)N * NHEAD * 4);
    float* ad1     = (float*)alloc((size_t)N * NHEAD * 4);
    float* as2     = (float*)alloc((size_t)N * NHEAD * 4);
    float* ad2     = (float*)alloc((size_t)N * NHEAD * 4);
    (void)ws_size;

    // ---- CSR build (shared by both layers) ----
    hipMemsetAsync(deg, 0, (size_t)N * 4, stream);
    int eb = (E + 255) / 256;
    hist_kernel<<<eb, 256, 0, stream>>>(dst, E, deg);
    scan_kernel<<<1, 1024, 0, stream>>>(deg, row_ptr, cursor, N);
    scatter_kernel<<<eb, 256, 0, stream>>>(src, dst, E, cursor, col);

    const int gblocks = (N + 63) / 64;

    // ---- layer 1 ----
    gemm128<<<gblocks, 256, 0, stream>>>(x, W1, h1, N);
    attn_logits<<<N, 128, 0, stream>>>(h1, att_s1, att_d1, as1, ad1, N);
    aggregate<<<N, 128, 0, stream>>>(h1, as1, ad1, row_ptr, col, b1, hx, nullptr, N, 1);

    // ---- layer 2 ----
    gemm128<<<gblocks, 256, 0, stream>>>(hx, W2, h1, N);   // h1 reused as h2
    attn_logits<<<N, 128, 0, stream>>>(h1, att_s2, att_d2, as2, ad2, N);
    aggregate<<<N, 128, 0, stream>>>(h1, as2, ad2, row_ptr, col, b2,
                                     out, out + (size_t)N * FDIM, N, 0);
}

// Round 2
// 671.412 us; speedup vs baseline: 1.1991x; 1.1991x over previous
//
#include <hip/hip_runtime.h>
#include <hip/hip_bf16.h>

// GAT, 2 layers. N=50000, F=128, H=4, C=32, E=1.6M (+N self-loops).
// R2: aggregate edge-loop unrolled x8 (8 concurrent gathers -> hide ~900cy
// load latency), attn logits fused into GEMM epilogue, int4 scan.

#define FDIM 128
#define NHEAD 4

// ---- GEMM: C[M][128] = A[M][128] @ B[128][128], fp32; fused a_s/a_d ------
__global__ __launch_bounds__(256) void gemm128(const float* __restrict__ A,
                                               const float* __restrict__ B,
                                               float* __restrict__ C,
                                               const float* __restrict__ att_s,
                                               const float* __restrict__ att_d,
                                               float* __restrict__ a_s,
                                               float* __restrict__ a_d, int M) {
    __shared__ float As[128 * 64];    // [k][m] (transposed)  32 KB
    __shared__ float Bs[128 * 128];   // [k][n]               64 KB
    const int tid = threadIdx.x;
    const int bm = blockIdx.x * 64;

    #pragma unroll
    for (int i = 0; i < 16; i++) {
        int idx = tid + i * 256;
        ((float4*)Bs)[idx] = ((const float4*)B)[idx];
    }
    #pragma unroll
    for (int i = 0; i < 8; i++) {
        int idx = tid + i * 256;      // float4 index
        int row = idx >> 5;           // 0..63
        int k4  = idx & 31;           // 0..31
        int grow = bm + row;
        float4 v = make_float4(0.f, 0.f, 0.f, 0.f);
        if (grow < M) v = ((const float4*)A)[grow * 32 + k4];
        As[(k4 * 4 + 0) * 64 + row] = v.x;
        As[(k4 * 4 + 1) * 64 + row] = v.y;
        As[(k4 * 4 + 2) * 64 + row] = v.z;
        As[(k4 * 4 + 3) * 64 + row] = v.w;
    }
    __syncthreads();

    const int mg = tid >> 5;   // 0..7  -> rows mg*8..mg*8+7
    const int ng = tid & 31;   // cols ng*4..ng*4+3
    float acc[8][4] = {};
    const float* Ap = &As[mg * 8];
    const float* Bp = &Bs[ng * 4];
    #pragma unroll 4
    for (int k = 0; k < 128; k++) {
        float4 a0 = *(const float4*)(Ap + k * 64);
        float4 a1 = *(const float4*)(Ap + k * 64 + 4);
        float4 b  = *(const float4*)(Bp + k * 128);
        float av[8] = {a0.x, a0.y, a0.z, a0.w, a1.x, a1.y, a1.z, a1.w};
        float bv[4] = {b.x, b.y, b.z, b.w};
        #pragma unroll
        for (int i = 0; i < 8; i++)
            #pragma unroll
            for (int j = 0; j < 4; j++)
                acc[i][j] += av[i] * bv[j];
    }

    // epilogue: store C rows + fused attention logits per row/head.
    // thread's 4 cols (ng*4..ng*4+3) lie in head ng>>3; lanes [head*8..head*8+7]
    // within each 32-lane half hold that head's partials -> 3-step shfl_xor.
    const float4 atS = ((const float4*)att_s)[ng];
    const float4 atD = ((const float4*)att_d)[ng];
    #pragma unroll
    for (int i = 0; i < 8; i++) {
        int grow = bm + mg * 8 + i;
        float ps = acc[i][0] * atS.x + acc[i][1] * atS.y + acc[i][2] * atS.z + acc[i][3] * atS.w;
        float pd = acc[i][0] * atD.x + acc[i][1] * atD.y + acc[i][2] * atD.z + acc[i][3] * atD.w;
        ps += __shfl_xor(ps, 1, 64); pd += __shfl_xor(pd, 1, 64);
        ps += __shfl_xor(ps, 2, 64); pd += __shfl_xor(pd, 2, 64);
        ps += __shfl_xor(ps, 4, 64); pd += __shfl_xor(pd, 4, 64);
        if (grow < M) {
            ((float4*)C)[grow * 32 + ng] =
                make_float4(acc[i][0], acc[i][1], acc[i][2], acc[i][3]);
            if ((ng & 7) == 0) {
                a_s[grow * NHEAD + (ng >> 3)] = ps;
                a_d[grow * NHEAD + (ng >> 3)] = pd;
            }
        }
    }
}

// ------------------------------ CSR build ---------------------------------
__global__ void hist_kernel(const int* __restrict__ dst, int E, int* __restrict__ deg) {
    int i = blockIdx.x * blockDim.x + threadIdx.x;
    if (i < E) atomicAdd(&deg[dst[i]], 1);
}

// single-block exclusive scan, 4 elems/thread (int4)
__global__ __launch_bounds__(1024) void scan_kernel(const int* __restrict__ deg,
                                                    int* __restrict__ row_ptr,
                                                    int* __restrict__ cursor, int n) {
    __shared__ int ws[16];
    __shared__ int wo[17];
    const int tid = threadIdx.x;
    const int lane = tid & 63, wid = tid >> 6;
    int offset = 0;
    for (int base = 0; base < n; base += 4096) {
        int i4 = base + tid * 4;
        int a = 0, b = 0, c = 0, d = 0;
        if (i4 + 3 < n) {
            int4 v = *(const int4*)&deg[i4];
            a = v.x; b = v.y; c = v.z; d = v.w;
        } else {
            if (i4 + 0 < n) a = deg[i4 + 0];
            if (i4 + 1 < n) b = deg[i4 + 1];
            if (i4 + 2 < n) c = deg[i4 + 2];
            if (i4 + 3 < n) d = deg[i4 + 3];
        }
        int t0 = a, t1 = a + b, t2 = t1 + c, t3 = t2 + d;
        int incl = t3;
        #pragma unroll
        for (int s = 1; s < 64; s <<= 1) {
            int t = __shfl_up(incl, s, 64);
            if (lane >= s) incl += t;
        }
        if (lane == 63) ws[wid] = incl;
        __syncthreads();
        if (wid == 0 && lane < 16) {
            int wincl = ws[lane];
            #pragma unroll
            for (int s = 1; s < 16; s <<= 1) {
                int t = __shfl_up(wincl, s, 64);
                if (lane >= s) wincl += t;
            }
            wo[lane + 1] = wincl;
            if (lane == 0) wo[0] = 0;
        }
        __syncthreads();
        int excl = offset + wo[wid] + incl - t3;   // exclusive before i4
        if (i4 + 0 < n) { row_ptr[i4 + 0] = excl;      cursor[i4 + 0] = excl; }
        if (i4 + 1 < n) { row_ptr[i4 + 1] = excl + t0; cursor[i4 + 1] = excl + t0; }
        if (i4 + 2 < n) { row_ptr[i4 + 2] = excl + t1; cursor[i4 + 2] = excl + t1; }
        if (i4 + 3 < n) { row_ptr[i4 + 3] = excl + t2; cursor[i4 + 3] = excl + t2; }
        offset += wo[16];
        __syncthreads();
    }
    if (tid == 0) row_ptr[n] = offset;
}

__global__ void scatter_kernel(const int* __restrict__ src, const int* __restrict__ dst,
                               int E, int* __restrict__ cursor, int* __restrict__ col) {
    int i = blockIdx.x * blockDim.x + threadIdx.x;
    if (i < E) {
        int pos = atomicAdd(&cursor[dst[i]], 1);
        col[pos] = src[i];
    }
}

// ------------- gather aggregation: softmax-weighted sum per dst ------------
// one block (128 thr) per dst node; thread = feature channel; head = c>>5.
// edge loop unrolled x8: 8 independent h-row gathers in flight (MLP).
__global__ __launch_bounds__(128) void aggregate(const float* __restrict__ h,
                                                 const float* __restrict__ a_s,
                                                 const float* __restrict__ a_d,
                                                 const int* __restrict__ row_ptr,
                                                 const int* __restrict__ col,
                                                 const float* __restrict__ bias,
                                                 float* __restrict__ out,
                                                 float* __restrict__ out2,
                                                 int n, int do_relu) {
    const int nid = blockIdx.x;
    const int c = threadIdx.x;
    const int hd = c >> 5;
    const float ad = a_d[nid * NHEAD + hd];

    // self loop (src = dst)
    float e = a_s[nid * NHEAD + hd] + ad;
    e = (e > 0.f) ? e : 0.2f * e;
    float den = __expf(e);
    float num = den * h[(size_t)nid * FDIM + c];

    const int beg = row_ptr[nid], end = row_ptr[nid + 1];
    int j = beg;
    for (; j + 8 <= end; j += 8) {
        int s[8];
        #pragma unroll
        for (int u = 0; u < 8; u++) s[u] = col[j + u];
        float v[8], el[8];
        #pragma unroll
        for (int u = 0; u < 8; u++) v[u] = h[(size_t)s[u] * FDIM + c];
        #pragma unroll
        for (int u = 0; u < 8; u++) el[u] = a_s[s[u] * NHEAD + hd];
        #pragma unroll
        for (int u = 0; u < 8; u++) {
            float e2 = el[u] + ad;
            e2 = (e2 > 0.f) ? e2 : 0.2f * e2;
            float w = __expf(e2);
            den += w;
            num += w * v[u];
        }
    }
    for (; j < end; j++) {
        int s = col[j];
        float e2 = a_s[s * NHEAD + hd] + ad;
        e2 = (e2 > 0.f) ? e2 : 0.2f * e2;
        float w = __expf(e2);
        den += w;
        num += w * h[(size_t)s * FDIM + c];
    }
    float o = num / den + bias[c];
    if (do_relu) o = fmaxf(o, 0.f);
    out[(size_t)nid * FDIM + c] = o;
    if (out2) out2[(size_t)nid * FDIM + c] = o;
}

// ------------------------------- launcher ----------------------------------
extern "C" void kernel_launch(void* const* d_in, const int* in_sizes, int n_in,
                              void* d_out, int out_size, void* d_ws, size_t ws_size,
                              hipStream_t stream) {
    const float* x        = (const float*)d_in[0];
    const int*   edge     = (const int*)d_in[1];
    const float* W1       = (const float*)d_in[2];
    const float* att_s1   = (const float*)d_in[3];
    const float* att_d1   = (const float*)d_in[4];
    const float* b1       = (const float*)d_in[5];
    const float* W2       = (const float*)d_in[6];
    const float* att_s2   = (const float*)d_in[7];
    const float* att_d2   = (const float*)d_in[8];
    const float* b2       = (const float*)d_in[9];
    float* out = (float*)d_out;

    const int N = in_sizes[0] / FDIM;         // 50000
    const int E = in_sizes[1] / 2;            // 1600000
    const int* src = edge;
    const int* dst = edge + E;

    char* w = (char*)d_ws;
    size_t off = 0;
    auto alloc = [&](size_t bytes) { void* p = w + off; off = (off + bytes + 255) & ~(size_t)255; return p; };
    int*   deg     = (int*)alloc((size_t)N * 4);
    int*   row_ptr = (int*)alloc((size_t)(N + 1) * 4);
    int*   cursor  = (int*)alloc((size_t)N * 4);
    int*   col     = (int*)alloc((size_t)E * 4);
    float* h1      = (float*)alloc((size_t)N * FDIM * 4);   // reused as h2
    float* hx      = (float*)alloc((size_t)N * FDIM * 4);
    float* as1     = (float*)alloc((size_t)N * NHEAD * 4);
    float* ad1     = (float*)alloc((size_t)N * NHEAD * 4);
    float* as2     = (float*)alloc((size_t)N * NHEAD * 4);
    float* ad2     = (float*)alloc((size_t)N * NHEAD * 4);
    (void)ws_size;

    // ---- CSR build (shared by both layers) ----
    hipMemsetAsync(deg, 0, (size_t)N * 4, stream);
    int eb = (E + 255) / 256;
    hist_kernel<<<eb, 256, 0, stream>>>(dst, E, deg);
    scan_kernel<<<1, 1024, 0, stream>>>(deg, row_ptr, cursor, N);
    scatter_kernel<<<eb, 256, 0, stream>>>(src, dst, E, cursor, col);

    const int gblocks = (N + 63) / 64;

    // ---- layer 1 ----
    gemm128<<<gblocks, 256, 0, stream>>>(x, W1, h1, att_s1, att_d1, as1, ad1, N);
    aggregate<<<N, 128, 0, stream>>>(h1, as1, ad1, row_ptr, col, b1, hx, nullptr, N, 1);

    // ---- layer 2 ----
    gemm128<<<gblocks, 256, 0, stream>>>(hx, W2, h1, att_s2, att_d2, as2, ad2, N);
    aggregate<<<N, 128, 0, stream>>>(h1, as2, ad2, row_ptr, col, b2,
                                     out, out + (size_t)N * FDIM, N, 0);
}

// Round 3
// 493.932 us; speedup vs baseline: 1.6299x; 1.3593x over previous
//
#include <hip/hip_runtime.h>
#include <hip/hip_bf16.h>

// GAT, 2 layers. N=50000, F=128, H=4, C=32, E=1.6M (+N self-loops).
// R3: CSR build rewritten as 2-level bucket partition to kill the 16x
// write amplification of the naive scatter (101MB -> ~22MB HBM writes).
// Aggregate: gather-based softmax, edge loop unrolled x8. Attn logits
// fused into GEMM epilogue.

#define FDIM 128
#define NHEAD 4
#define NB 512          // dst buckets for CSR build

// ---- GEMM: C[M][128] = A[M][128] @ B[128][128], fp32; fused a_s/a_d ------
__global__ __launch_bounds__(256) void gemm128(const float* __restrict__ A,
                                               const float* __restrict__ B,
                                               float* __restrict__ C,
                                               const float* __restrict__ att_s,
                                               const float* __restrict__ att_d,
                                               float* __restrict__ a_s,
                                               float* __restrict__ a_d, int M) {
    __shared__ float As[128 * 64];    // [k][m] (transposed)  32 KB
    __shared__ float Bs[128 * 128];   // [k][n]               64 KB
    const int tid = threadIdx.x;
    const int bm = blockIdx.x * 64;

    #pragma unroll
    for (int i = 0; i < 16; i++) {
        int idx = tid + i * 256;
        ((float4*)Bs)[idx] = ((const float4*)B)[idx];
    }
    #pragma unroll
    for (int i = 0; i < 8; i++) {
        int idx = tid + i * 256;      // float4 index
        int row = idx >> 5;           // 0..63
        int k4  = idx & 31;           // 0..31
        int grow = bm + row;
        float4 v = make_float4(0.f, 0.f, 0.f, 0.f);
        if (grow < M) v = ((const float4*)A)[grow * 32 + k4];
        As[(k4 * 4 + 0) * 64 + row] = v.x;
        As[(k4 * 4 + 1) * 64 + row] = v.y;
        As[(k4 * 4 + 2) * 64 + row] = v.z;
        As[(k4 * 4 + 3) * 64 + row] = v.w;
    }
    __syncthreads();

    const int mg = tid >> 5;   // rows mg*8..mg*8+7
    const int ng = tid & 31;   // cols ng*4..ng*4+3
    float acc[8][4] = {};
    const float* Ap = &As[mg * 8];
    const float* Bp = &Bs[ng * 4];
    #pragma unroll 4
    for (int k = 0; k < 128; k++) {
        float4 a0 = *(const float4*)(Ap + k * 64);
        float4 a1 = *(const float4*)(Ap + k * 64 + 4);
        float4 b  = *(const float4*)(Bp + k * 128);
        float av[8] = {a0.x, a0.y, a0.z, a0.w, a1.x, a1.y, a1.z, a1.w};
        float bv[4] = {b.x, b.y, b.z, b.w};
        #pragma unroll
        for (int i = 0; i < 8; i++)
            #pragma unroll
            for (int j = 0; j < 4; j++)
                acc[i][j] += av[i] * bv[j];
    }

    const float4 atS = ((const float4*)att_s)[ng];
    const float4 atD = ((const float4*)att_d)[ng];
    #pragma unroll
    for (int i = 0; i < 8; i++) {
        int grow = bm + mg * 8 + i;
        float ps = acc[i][0] * atS.x + acc[i][1] * atS.y + acc[i][2] * atS.z + acc[i][3] * atS.w;
        float pd = acc[i][0] * atD.x + acc[i][1] * atD.y + acc[i][2] * atD.z + acc[i][3] * atD.w;
        ps += __shfl_xor(ps, 1, 64); pd += __shfl_xor(pd, 1, 64);
        ps += __shfl_xor(ps, 2, 64); pd += __shfl_xor(pd, 2, 64);
        ps += __shfl_xor(ps, 4, 64); pd += __shfl_xor(pd, 4, 64);
        if (grow < M) {
            ((float4*)C)[grow * 32 + ng] =
                make_float4(acc[i][0], acc[i][1], acc[i][2], acc[i][3]);
            if ((ng & 7) == 0) {
                a_s[grow * NHEAD + (ng >> 3)] = ps;
                a_d[grow * NHEAD + (ng >> 3)] = pd;
            }
        }
    }
}

// ------------------------------ CSR build ---------------------------------
// bucket b covers dst in [b*npb, (b+1)*npb); bucket = (dst*magic)>>40 with
// magic = 2^40/npb + 1 (exact for dst < 2^40/npb, ample).

__global__ __launch_bounds__(256) void bucket_hist(const int* __restrict__ dst, int E,
                                                   unsigned long long magic,
                                                   int* __restrict__ bcnt) {
    __shared__ int sh[NB];
    const int t = threadIdx.x;
    for (int i = t; i < NB; i += 256) sh[i] = 0;
    __syncthreads();
    for (int i = blockIdx.x * blockDim.x + t; i < E; i += gridDim.x * blockDim.x) {
        int b = (int)(((unsigned long long)(unsigned)dst[i] * magic) >> 40);
        atomicAdd(&sh[b], 1);
    }
    __syncthreads();
    for (int i = t; i < NB; i += 256)
        if (sh[i]) atomicAdd(&bcnt[i], sh[i]);
}

// single block: exclusive scan of NB=512 counts -> bbase/bcursor; row_ptr[N]=E
__global__ __launch_bounds__(256) void bucket_scan(const int* __restrict__ bcnt,
                                                   int* __restrict__ bbase,
                                                   int* __restrict__ bcursor,
                                                   int* __restrict__ row_ptr,
                                                   int N, int E) {
    __shared__ int wsum[4];
    const int t = threadIdx.x, lane = t & 63, wid = t >> 6;
    int v0 = bcnt[2 * t], v1 = bcnt[2 * t + 1];
    int s = v0 + v1, incl = s;
    #pragma unroll
    for (int o = 1; o < 64; o <<= 1) {
        int u = __shfl_up(incl, o, 64);
        if (lane >= o) incl += u;
    }
    if (lane == 63) wsum[wid] = incl;
    __syncthreads();
    if (t == 0) {
        int a = 0;
        #pragma unroll
        for (int i = 0; i < 4; i++) { int x = wsum[i]; wsum[i] = a; a += x; }
    }
    __syncthreads();
    int excl = wsum[wid] + incl - s;
    bbase[2 * t] = excl;          bcursor[2 * t] = excl;
    bbase[2 * t + 1] = excl + v0; bcursor[2 * t + 1] = excl + v0;
    if (t == 0) { bbase[NB] = E; row_ptr[N] = E; }
}

// partition edges into bucket-grouped ebuf (int2{src,dst}); one atomic per
// bucket per block for range reservation -> writes are temporally clustered.
__global__ __launch_bounds__(256) void partition(const int* __restrict__ src,
                                                 const int* __restrict__ dst, int E,
                                                 unsigned long long magic,
                                                 int* __restrict__ bcursor,
                                                 int2* __restrict__ ebuf) {
    __shared__ int shc[NB];    // per-bucket count in this block
    __shared__ int shb[NB];    // reserved global base
    __shared__ int shcur[NB];  // local cursor
    const int t = threadIdx.x;
    for (int i = t; i < NB; i += 256) shc[i] = 0;
    __syncthreads();
    const int e0 = blockIdx.x * 4096;
    int myb[16], mys[16], myd[16];
    #pragma unroll
    for (int u = 0; u < 16; u++) {
        int i = e0 + u * 256 + t;
        if (i < E) {
            mys[u] = src[i];
            myd[u] = dst[i];
            int b = (int)(((unsigned long long)(unsigned)myd[u] * magic) >> 40);
            myb[u] = b;
            atomicAdd(&shc[b], 1);
        } else myb[u] = -1;
    }
    __syncthreads();
    for (int i = t; i < NB; i += 256) {
        int c = shc[i];
        shcur[i] = 0;
        if (c) shb[i] = atomicAdd(&bcursor[i], c);
    }
    __syncthreads();
    #pragma unroll
    for (int u = 0; u < 16; u++) {
        if (myb[u] >= 0) {
            int o = atomicAdd(&shcur[myb[u]], 1);
            ebuf[shb[myb[u]] + o] = make_int2(mys[u], myd[u]);
        }
    }
}

// one block per bucket: local degree count -> local scan -> row_ptr for the
// bucket's nodes + col placement into a contiguous ~25KB region (L2-local).
__global__ __launch_bounds__(256) void build_bucket(const int2* __restrict__ ebuf,
                                                    const int* __restrict__ bbase,
                                                    int npb, int N,
                                                    int* __restrict__ row_ptr,
                                                    int* __restrict__ col) {
    __shared__ int degl[256];
    __shared__ int curl[256];
    const int b = blockIdx.x;
    const int t = threadIdx.x, lane = t & 63, wid = t >> 6;
    const int base = bbase[b];
    const int cnt = bbase[b + 1] - base;
    const int node0 = b * npb;
    for (int i = t; i < npb; i += 256) degl[i] = 0;
    __syncthreads();
    for (int i = t; i < cnt; i += 256) {
        int d = ebuf[base + i].y;
        atomicAdd(&degl[d - node0], 1);
    }
    __syncthreads();
    if (wid == 0) {
        int run = 0;
        for (int c = 0; c * 64 < npb; c++) {
            int idx = c * 64 + lane;
            int v = (idx < npb) ? degl[idx] : 0;
            int incl = v;
            #pragma unroll
            for (int o = 1; o < 64; o <<= 1) {
                int u = __shfl_up(incl, o, 64);
                if (lane >= o) incl += u;
            }
            int excl = incl - v + run;
            if (idx < npb) {
                curl[idx] = excl;
                int node = node0 + idx;
                if (node < N) row_ptr[node] = base + excl;
            }
            run += __shfl(incl, 63, 64);
        }
    }
    __syncthreads();
    for (int i = t; i < cnt; i += 256) {
        int2 ed = ebuf[base + i];
        int p = atomicAdd(&curl[ed.y - node0], 1);
        col[base + p] = ed.x;
    }
}

// ------------- gather aggregation: softmax-weighted sum per dst ------------
__global__ __launch_bounds__(128) void aggregate(const float* __restrict__ h,
                                                 const float* __restrict__ a_s,
                                                 const float* __restrict__ a_d,
                                                 const int* __restrict__ row_ptr,
                                                 const int* __restrict__ col,
                                                 const float* __restrict__ bias,
                                                 float* __restrict__ out,
                                                 float* __restrict__ out2,
                                                 int n, int do_relu) {
    const int nid = blockIdx.x;
    const int c = threadIdx.x;
    const int hd = c >> 5;
    const float ad = a_d[nid * NHEAD + hd];

    float e = a_s[nid * NHEAD + hd] + ad;        // self loop
    e = (e > 0.f) ? e : 0.2f * e;
    float den = __expf(e);
    float num = den * h[(size_t)nid * FDIM + c];

    const int beg = row_ptr[nid], end = row_ptr[nid + 1];
    int j = beg;
    for (; j + 8 <= end; j += 8) {
        int s[8];
        #pragma unroll
        for (int u = 0; u < 8; u++) s[u] = col[j + u];
        float v[8], el[8];
        #pragma unroll
        for (int u = 0; u < 8; u++) v[u] = h[(size_t)s[u] * FDIM + c];
        #pragma unroll
        for (int u = 0; u < 8; u++) el[u] = a_s[s[u] * NHEAD + hd];
        #pragma unroll
        for (int u = 0; u < 8; u++) {
            float e2 = el[u] + ad;
            e2 = (e2 > 0.f) ? e2 : 0.2f * e2;
            float w = __expf(e2);
            den += w;
            num += w * v[u];
        }
    }
    for (; j < end; j++) {
        int s = col[j];
        float e2 = a_s[s * NHEAD + hd] + ad;
        e2 = (e2 > 0.f) ? e2 : 0.2f * e2;
        float w = __expf(e2);
        den += w;
        num += w * h[(size_t)s * FDIM + c];
    }
    float o = num / den + bias[c];
    if (do_relu) o = fmaxf(o, 0.f);
    out[(size_t)nid * FDIM + c] = o;
    if (out2) out2[(size_t)nid * FDIM + c] = o;
}

// ------------------------------- launcher ----------------------------------
extern "C" void kernel_launch(void* const* d_in, const int* in_sizes, int n_in,
                              void* d_out, int out_size, void* d_ws, size_t ws_size,
                              hipStream_t stream) {
    const float* x        = (const float*)d_in[0];
    const int*   edge     = (const int*)d_in[1];
    const float* W1       = (const float*)d_in[2];
    const float* att_s1   = (const float*)d_in[3];
    const float* att_d1   = (const float*)d_in[4];
    const float* b1       = (const float*)d_in[5];
    const float* W2       = (const float*)d_in[6];
    const float* att_s2   = (const float*)d_in[7];
    const float* att_d2   = (const float*)d_in[8];
    const float* b2       = (const float*)d_in[9];
    float* out = (float*)d_out;

    const int N = in_sizes[0] / FDIM;         // 50000
    const int E = in_sizes[1] / 2;            // 1600000
    const int* src = edge;
    const int* dst = edge + E;

    const int npb = (N + NB - 1) / NB;        // 98
    const unsigned long long magic = ((1ull << 40) / (unsigned long long)npb) + 1;

    char* w = (char*)d_ws;
    size_t off = 0;
    auto alloc = [&](size_t bytes) { void* p = w + off; off = (off + bytes + 255) & ~(size_t)255; return p; };
    int*   row_ptr = (int*)alloc((size_t)(N + 1) * 4);
    int*   col     = (int*)alloc((size_t)E * 4);
    int*   bcnt    = (int*)alloc((size_t)NB * 4);
    int*   bbase   = (int*)alloc((size_t)(NB + 1) * 4);
    int*   bcursor = (int*)alloc((size_t)NB * 4);
    float* h1      = (float*)alloc((size_t)N * FDIM * 4);   // reused as h2
    float* hx      = (float*)alloc((size_t)N * FDIM * 4);   // layer-1 out; ebuf alias
    float* as1     = (float*)alloc((size_t)N * NHEAD * 4);
    float* ad1     = (float*)alloc((size_t)N * NHEAD * 4);
    float* as2     = (float*)alloc((size_t)N * NHEAD * 4);
    float* ad2     = (float*)alloc((size_t)N * NHEAD * 4);
    int2*  ebuf    = (int2*)hx;   // dead before aggregate-1 writes hx
    (void)ws_size;

    // ---- CSR build (bucketed; shared by both layers) ----
    hipMemsetAsync(bcnt, 0, (size_t)NB * 4, stream);
    bucket_hist<<<1024, 256, 0, stream>>>(dst, E, magic, bcnt);
    bucket_scan<<<1, 256, 0, stream>>>(bcnt, bbase, bcursor, row_ptr, N, E);
    partition<<<(E + 4095) / 4096, 256, 0, stream>>>(src, dst, E, magic, bcursor, ebuf);
    build_bucket<<<NB, 256, 0, stream>>>(ebuf, bbase, npb, N, row_ptr, col);

    const int gblocks = (N + 63) / 64;

    // ---- layer 1 ----
    gemm128<<<gblocks, 256, 0, stream>>>(x, W1, h1, att_s1, att_d1, as1, ad1, N);
    aggregate<<<N, 128, 0, stream>>>(h1, as1, ad1, row_ptr, col, b1, hx, nullptr, N, 1);

    // ---- layer 2 ----
    gemm128<<<gblocks, 256, 0, stream>>>(hx, W2, h1, att_s2, att_d2, as2, ad2, N);
    aggregate<<<N, 128, 0, stream>>>(h1, as2, ad2, row_ptr, col, b2,
                                     out, out + (size_t)N * FDIM, N, 0);
}

// Round 4
// 386.347 us; speedup vs baseline: 2.0838x; 1.2785x over previous
//
#include <hip/hip_runtime.h>
#include <hip/hip_bf16.h>

// GAT, 2 layers. N=50000, F=128, H=4, C=32, E=1.6M (+N self-loops).
// R4: h stored bf16 (halves gather bytes); aggregate = 1 wave/node,
// 2 feats/lane (256B row = 1 wave transaction, half the redundant exp).
// Logits still fp32 (computed in GEMM epilogue before rounding).
// CSR: 2-level bucket partition (R3). Edge loop unrolled x8.

#define FDIM 128
#define NHEAD 4
#define NB 512          // dst buckets for CSR build

__device__ inline unsigned short f2bf(float f) {
    union { float f; unsigned u; } v; v.f = f;
    unsigned r = v.u + 0x7fff + ((v.u >> 16) & 1);   // RNE
    return (unsigned short)(r >> 16);
}
__device__ inline float2 bf2f(unsigned v) {
    union { unsigned u; float f; } a, b;
    a.u = v << 16;            // low half  = feature 2c
    b.u = v & 0xffff0000u;    // high half = feature 2c+1
    return make_float2(a.f, b.f);
}

// ---- GEMM: C[M][128](bf16) = A[M][128](f32) @ B[128][128]; fused a_s/a_d --
__global__ __launch_bounds__(256) void gemm128(const float* __restrict__ A,
                                               const float* __restrict__ B,
                                               unsigned short* __restrict__ C,
                                               const float* __restrict__ att_s,
                                               const float* __restrict__ att_d,
                                               float* __restrict__ a_s,
                                               float* __restrict__ a_d, int M) {
    __shared__ float As[128 * 64];    // [k][m] (transposed)  32 KB
    __shared__ float Bs[128 * 128];   // [k][n]               64 KB
    const int tid = threadIdx.x;
    const int bm = blockIdx.x * 64;

    #pragma unroll
    for (int i = 0; i < 16; i++) {
        int idx = tid + i * 256;
        ((float4*)Bs)[idx] = ((const float4*)B)[idx];
    }
    #pragma unroll
    for (int i = 0; i < 8; i++) {
        int idx = tid + i * 256;      // float4 index
        int row = idx >> 5;           // 0..63
        int k4  = idx & 31;           // 0..31
        int grow = bm + row;
        float4 v = make_float4(0.f, 0.f, 0.f, 0.f);
        if (grow < M) v = ((const float4*)A)[grow * 32 + k4];
        As[(k4 * 4 + 0) * 64 + row] = v.x;
        As[(k4 * 4 + 1) * 64 + row] = v.y;
        As[(k4 * 4 + 2) * 64 + row] = v.z;
        As[(k4 * 4 + 3) * 64 + row] = v.w;
    }
    __syncthreads();

    const int mg = tid >> 5;   // rows mg*8..mg*8+7
    const int ng = tid & 31;   // cols ng*4..ng*4+3
    float acc[8][4] = {};
    const float* Ap = &As[mg * 8];
    const float* Bp = &Bs[ng * 4];
    #pragma unroll 4
    for (int k = 0; k < 128; k++) {
        float4 a0 = *(const float4*)(Ap + k * 64);
        float4 a1 = *(const float4*)(Ap + k * 64 + 4);
        float4 b  = *(const float4*)(Bp + k * 128);
        float av[8] = {a0.x, a0.y, a0.z, a0.w, a1.x, a1.y, a1.z, a1.w};
        float bv[4] = {b.x, b.y, b.z, b.w};
        #pragma unroll
        for (int i = 0; i < 8; i++)
            #pragma unroll
            for (int j = 0; j < 4; j++)
                acc[i][j] += av[i] * bv[j];
    }

    const float4 atS = ((const float4*)att_s)[ng];
    const float4 atD = ((const float4*)att_d)[ng];
    #pragma unroll
    for (int i = 0; i < 8; i++) {
        int grow = bm + mg * 8 + i;
        float ps = acc[i][0] * atS.x + acc[i][1] * atS.y + acc[i][2] * atS.z + acc[i][3] * atS.w;
        float pd = acc[i][0] * atD.x + acc[i][1] * atD.y + acc[i][2] * atD.z + acc[i][3] * atD.w;
        ps += __shfl_xor(ps, 1, 64); pd += __shfl_xor(pd, 1, 64);
        ps += __shfl_xor(ps, 2, 64); pd += __shfl_xor(pd, 2, 64);
        ps += __shfl_xor(ps, 4, 64); pd += __shfl_xor(pd, 4, 64);
        if (grow < M) {
            ((ushort4*)C)[grow * 32 + ng] =
                make_ushort4(f2bf(acc[i][0]), f2bf(acc[i][1]),
                             f2bf(acc[i][2]), f2bf(acc[i][3]));
            if ((ng & 7) == 0) {
                a_s[grow * NHEAD + (ng >> 3)] = ps;
                a_d[grow * NHEAD + (ng >> 3)] = pd;
            }
        }
    }
}

// ------------------------------ CSR build ---------------------------------
__global__ __launch_bounds__(256) void bucket_hist(const int* __restrict__ dst, int E,
                                                   unsigned long long magic,
                                                   int* __restrict__ bcnt) {
    __shared__ int sh[NB];
    const int t = threadIdx.x;
    for (int i = t; i < NB; i += 256) sh[i] = 0;
    __syncthreads();
    for (int i = blockIdx.x * blockDim.x + t; i < E; i += gridDim.x * blockDim.x) {
        int b = (int)(((unsigned long long)(unsigned)dst[i] * magic) >> 40);
        atomicAdd(&sh[b], 1);
    }
    __syncthreads();
    for (int i = t; i < NB; i += 256)
        if (sh[i]) atomicAdd(&bcnt[i], sh[i]);
}

__global__ __launch_bounds__(256) void bucket_scan(const int* __restrict__ bcnt,
                                                   int* __restrict__ bbase,
                                                   int* __restrict__ bcursor,
                                                   int* __restrict__ row_ptr,
                                                   int N, int E) {
    __shared__ int wsum[4];
    const int t = threadIdx.x, lane = t & 63, wid = t >> 6;
    int v0 = bcnt[2 * t], v1 = bcnt[2 * t + 1];
    int s = v0 + v1, incl = s;
    #pragma unroll
    for (int o = 1; o < 64; o <<= 1) {
        int u = __shfl_up(incl, o, 64);
        if (lane >= o) incl += u;
    }
    if (lane == 63) wsum[wid] = incl;
    __syncthreads();
    if (t == 0) {
        int a = 0;
        #pragma unroll
        for (int i = 0; i < 4; i++) { int x = wsum[i]; wsum[i] = a; a += x; }
    }
    __syncthreads();
    int excl = wsum[wid] + incl - s;
    bbase[2 * t] = excl;          bcursor[2 * t] = excl;
    bbase[2 * t + 1] = excl + v0; bcursor[2 * t + 1] = excl + v0;
    if (t == 0) { bbase[NB] = E; row_ptr[N] = E; }
}

__global__ __launch_bounds__(256) void partition(const int* __restrict__ src,
                                                 const int* __restrict__ dst, int E,
                                                 unsigned long long magic,
                                                 int* __restrict__ bcursor,
                                                 int2* __restrict__ ebuf) {
    __shared__ int shc[NB];    // per-bucket count in this block
    __shared__ int shb[NB];    // reserved global base
    __shared__ int shcur[NB];  // local cursor
    const int t = threadIdx.x;
    for (int i = t; i < NB; i += 256) shc[i] = 0;
    __syncthreads();
    const int e0 = blockIdx.x * 4096;
    int myb[16], mys[16], myd[16];
    #pragma unroll
    for (int u = 0; u < 16; u++) {
        int i = e0 + u * 256 + t;
        if (i < E) {
            mys[u] = src[i];
            myd[u] = dst[i];
            int b = (int)(((unsigned long long)(unsigned)myd[u] * magic) >> 40);
            myb[u] = b;
            atomicAdd(&shc[b], 1);
        } else myb[u] = -1;
    }
    __syncthreads();
    for (int i = t; i < NB; i += 256) {
        int c = shc[i];
        shcur[i] = 0;
        if (c) shb[i] = atomicAdd(&bcursor[i], c);
    }
    __syncthreads();
    #pragma unroll
    for (int u = 0; u < 16; u++) {
        if (myb[u] >= 0) {
            int o = atomicAdd(&shcur[myb[u]], 1);
            ebuf[shb[myb[u]] + o] = make_int2(mys[u], myd[u]);
        }
    }
}

__global__ __launch_bounds__(256) void build_bucket(const int2* __restrict__ ebuf,
                                                    const int* __restrict__ bbase,
                                                    int npb, int N,
                                                    int* __restrict__ row_ptr,
                                                    int* __restrict__ col) {
    __shared__ int degl[256];
    __shared__ int curl[256];
    const int b = blockIdx.x;
    const int t = threadIdx.x, lane = t & 63, wid = t >> 6;
    const int base = bbase[b];
    const int cnt = bbase[b + 1] - base;
    const int node0 = b * npb;
    for (int i = t; i < npb; i += 256) degl[i] = 0;
    __syncthreads();
    for (int i = t; i < cnt; i += 256) {
        int d = ebuf[base + i].y;
        atomicAdd(&degl[d - node0], 1);
    }
    __syncthreads();
    if (wid == 0) {
        int run = 0;
        for (int c = 0; c * 64 < npb; c++) {
            int idx = c * 64 + lane;
            int v = (idx < npb) ? degl[idx] : 0;
            int incl = v;
            #pragma unroll
            for (int o = 1; o < 64; o <<= 1) {
                int u = __shfl_up(incl, o, 64);
                if (lane >= o) incl += u;
            }
            int excl = incl - v + run;
            if (idx < npb) {
                curl[idx] = excl;
                int node = node0 + idx;
                if (node < N) row_ptr[node] = base + excl;
            }
            run += __shfl(incl, 63, 64);
        }
    }
    __syncthreads();
    for (int i = t; i < cnt; i += 256) {
        int2 ed = ebuf[base + i];
        int p = atomicAdd(&curl[ed.y - node0], 1);
        col[base + p] = ed.x;
    }
}

// ------------- gather aggregation: softmax-weighted sum per dst ------------
// 1 wave per dst node; lane c handles features 2c,2c+1 (one uint bf16x2 load
// -> a full 256B h row is a single wave transaction). head = c>>4.
__global__ __launch_bounds__(64) void aggregate(const unsigned short* __restrict__ h,
                                                const float* __restrict__ a_s,
                                                const float* __restrict__ a_d,
                                                const int* __restrict__ row_ptr,
                                                const int* __restrict__ col,
                                                const float* __restrict__ bias,
                                                float* __restrict__ out,
                                                float* __restrict__ out2,
                                                int n, int do_relu) {
    const int nid = blockIdx.x;
    const int c = threadIdx.x;          // 0..63
    const int hd = c >> 4;
    const float ad = a_d[nid * NHEAD + hd];
    const unsigned* __restrict__ h2 = (const unsigned*)h;

    float e = a_s[nid * NHEAD + hd] + ad;        // self loop
    e = (e > 0.f) ? e : 0.2f * e;
    float den = __expf(e);
    float2 hv = bf2f(h2[(size_t)nid * 64 + c]);
    float num0 = den * hv.x, num1 = den * hv.y;

    const int beg = row_ptr[nid], end = row_ptr[nid + 1];
    int j = beg;
    for (; j + 8 <= end; j += 8) {
        int s[8];
        #pragma unroll
        for (int u = 0; u < 8; u++) s[u] = col[j + u];
        unsigned v[8]; float el[8];
        #pragma unroll
        for (int u = 0; u < 8; u++) v[u] = h2[(size_t)s[u] * 64 + c];
        #pragma unroll
        for (int u = 0; u < 8; u++) el[u] = a_s[s[u] * NHEAD + hd];
        #pragma unroll
        for (int u = 0; u < 8; u++) {
            float e2 = el[u] + ad;
            e2 = (e2 > 0.f) ? e2 : 0.2f * e2;
            float w = __expf(e2);
            den += w;
            float2 f = bf2f(v[u]);
            num0 += w * f.x;
            num1 += w * f.y;
        }
    }
    for (; j < end; j++) {
        int s = col[j];
        float e2 = a_s[s * NHEAD + hd] + ad;
        e2 = (e2 > 0.f) ? e2 : 0.2f * e2;
        float w = __expf(e2);
        den += w;
        float2 f = bf2f(h2[(size_t)s * 64 + c]);
        num0 += w * f.x;
        num1 += w * f.y;
    }
    float2 bv = ((const float2*)bias)[c];
    float rd = 1.0f / den;
    float o0 = num0 * rd + bv.x;
    float o1 = num1 * rd + bv.y;
    if (do_relu) { o0 = fmaxf(o0, 0.f); o1 = fmaxf(o1, 0.f); }
    ((float2*)out)[(size_t)nid * 64 + c] = make_float2(o0, o1);
    if (out2) ((float2*)out2)[(size_t)nid * 64 + c] = make_float2(o0, o1);
}

// ------------------------------- launcher ----------------------------------
extern "C" void kernel_launch(void* const* d_in, const int* in_sizes, int n_in,
                              void* d_out, int out_size, void* d_ws, size_t ws_size,
                              hipStream_t stream) {
    const float* x        = (const float*)d_in[0];
    const int*   edge     = (const int*)d_in[1];
    const float* W1       = (const float*)d_in[2];
    const float* att_s1   = (const float*)d_in[3];
    const float* att_d1   = (const float*)d_in[4];
    const float* b1       = (const float*)d_in[5];
    const float* W2       = (const float*)d_in[6];
    const float* att_s2   = (const float*)d_in[7];
    const float* att_d2   = (const float*)d_in[8];
    const float* b2       = (const float*)d_in[9];
    float* out = (float*)d_out;

    const int N = in_sizes[0] / FDIM;         // 50000
    const int E = in_sizes[1] / 2;            // 1600000
    const int* src = edge;
    const int* dst = edge + E;

    const int npb = (N + NB - 1) / NB;        // 98
    const unsigned long long magic = ((1ull << 40) / (unsigned long long)npb) + 1;

    char* w = (char*)d_ws;
    size_t off = 0;
    auto alloc = [&](size_t bytes) { void* p = w + off; off = (off + bytes + 255) & ~(size_t)255; return p; };
    int*   row_ptr = (int*)alloc((size_t)(N + 1) * 4);
    int*   col     = (int*)alloc((size_t)E * 4);
    int*   bcnt    = (int*)alloc((size_t)NB * 4);
    int*   bbase   = (int*)alloc((size_t)(NB + 1) * 4);
    int*   bcursor = (int*)alloc((size_t)NB * 4);
    unsigned short* h1 = (unsigned short*)alloc((size_t)N * FDIM * 2);  // bf16, reused as h2
    float* hx      = (float*)alloc((size_t)N * FDIM * 4);   // layer-1 out; ebuf alias
    float* as1     = (float*)alloc((size_t)N * NHEAD * 4);
    float* ad1     = (float*)alloc((size_t)N * NHEAD * 4);
    float* as2     = (float*)alloc((size_t)N * NHEAD * 4);
    float* ad2     = (float*)alloc((size_t)N * NHEAD * 4);
    int2*  ebuf    = (int2*)hx;   // dead before aggregate-1 writes hx
    (void)ws_size;

    // ---- CSR build (bucketed; shared by both layers) ----
    hipMemsetAsync(bcnt, 0, (size_t)NB * 4, stream);
    bucket_hist<<<1024, 256, 0, stream>>>(dst, E, magic, bcnt);
    bucket_scan<<<1, 256, 0, stream>>>(bcnt, bbase, bcursor, row_ptr, N, E);
    partition<<<(E + 4095) / 4096, 256, 0, stream>>>(src, dst, E, magic, bcursor, ebuf);
    build_bucket<<<NB, 256, 0, stream>>>(ebuf, bbase, npb, N, row_ptr, col);

    const int gblocks = (N + 63) / 64;

    // ---- layer 1 ----
    gemm128<<<gblocks, 256, 0, stream>>>(x, W1, h1, att_s1, att_d1, as1, ad1, N);
    aggregate<<<N, 64, 0, stream>>>(h1, as1, ad1, row_ptr, col, b1, hx, nullptr, N, 1);

    // ---- layer 2 ----
    gemm128<<<gblocks, 256, 0, stream>>>(hx, W2, h1, att_s2, att_d2, as2, ad2, N);
    aggregate<<<N, 64, 0, stream>>>(h1, as2, ad2, row_ptr, col, b2,
                                    out, out + (size_t)N * FDIM, N, 0);
}

// Round 5
// 348.578 us; speedup vs baseline: 2.3096x; 1.1084x over previous
//
#include <hip/hip_runtime.h>
#include <hip/hip_bf16.h>

// GAT, 2 layers. N=50000, F=128, H=4, C=32, E=1.6M (+N self-loops).
// R5: GEMM -> split-bf16 MFMA (32x32x16), 3-term (hi*hi + lo*hi + hi*lo)
// for ~fp32 precision at MFMA rate. A: global->reg, split in regs (no LDS
// transpose -> kills the 6.2M bank conflicts of R4). B: prep kernel
// pre-splits W into XOR-swizzled [n][k] bf16; conflict-free ds_read_b128.
// Logits computed per (row,head) from bf16 h tile (head = aligned 32-col
// block => one thread owns a full head dot, no reduction).
// Aggregate (R4): 1 wave/node, bf16x2 loads, x8 unroll. CSR: R3 buckets.

#define FDIM 128
#define NHEAD 4
#define NB 512          // dst buckets for CSR build

typedef __attribute__((ext_vector_type(16))) float f32x16;
typedef __attribute__((ext_vector_type(8)))  short s16x8;

__device__ inline unsigned short f2bf(float f) {
    union { float f; unsigned u; } v; v.f = f;
    unsigned r = v.u + 0x7fff + ((v.u >> 16) & 1);   // RNE
    return (unsigned short)(r >> 16);
}
__device__ inline float2 bf2f(unsigned v) {
    union { unsigned u; float f; } a, b;
    a.u = v << 16;            // low half  = feature 2c
    b.u = v & 0xffff0000u;    // high half = feature 2c+1
    return make_float2(a.f, b.f);
}

// ---- prep: W[128][128] f32 -> transposed, split, swizzled bf16 hi/lo ----
// out[n*128 + ((k>>3)^(n&15))*8 + (k&7)]; hi = trunc, lo = trunc(f - hi).
__global__ __launch_bounds__(256) void prep_w(const float* __restrict__ W,
                                              short* __restrict__ Bhi,
                                              short* __restrict__ Blo) {
    const int t = threadIdx.x;
    for (int i = 0; i < 64; i++) {
        int e = i * 256 + t;          // e = k*128 + n
        int k = e >> 7, n = e & 127;
        float f = W[e];
        unsigned u = __float_as_uint(f);
        unsigned short hi = (unsigned short)(u >> 16);
        float rem = f - __uint_as_float(u & 0xffff0000u);
        unsigned short lo = (unsigned short)(__float_as_uint(rem) >> 16);
        int idx = n * 128 + ((((k >> 3) ^ (n & 15))) << 3) + (k & 7);
        Bhi[idx] = (short)hi;
        Blo[idx] = (short)lo;
    }
}

// ---- MFMA GEMM: H[M][128](bf16) = A[M][128](f32) @ W; fused a_s/a_d ------
// block: 64 rows x 128 cols; 4 waves as 2x2 of 32x32 tiles, 2 n-iters.
__global__ __launch_bounds__(256) void gemm_mfma(const float* __restrict__ A,
                                                 const short* __restrict__ Bghi,
                                                 const short* __restrict__ Bglo,
                                                 unsigned short* __restrict__ H,
                                                 const float* __restrict__ att_s,
                                                 const float* __restrict__ att_d,
                                                 float* __restrict__ a_s,
                                                 float* __restrict__ a_d, int M) {
    __shared__ short Bsm[2][16384];   // 64 KB: [hi/lo][n*128 + k']
    __shared__ float attsm[256];      // att_s[128], att_d[128]
    const int t = threadIdx.x;
    const int bm = blockIdx.x * 64;

    if (t < 128) attsm[t] = att_s[t];
    else         attsm[t] = att_d[t - 128];

    {   // stage B (pre-swizzled; verbatim 32KB+32KB copy)
        const uint4* ghi = (const uint4*)Bghi;
        const uint4* glo = (const uint4*)Bglo;
        uint4* shi = (uint4*)&Bsm[0][0];
        uint4* slo = (uint4*)&Bsm[1][0];
        #pragma unroll
        for (int i = 0; i < 8; i++) {
            shi[t + i * 256] = ghi[t + i * 256];
            slo[t + i * 256] = glo[t + i * 256];
        }
    }

    const int lane = t & 63;
    const int w = t >> 6;
    const int wr = w >> 1, wc = w & 1;     // wave tile: rows wr*32, cols wc*32
    const int m  = lane & 31, h2 = lane >> 5;
    const int grow = bm + wr * 32 + m;

    // A fragments: 8 k-chunks of 16; lane holds k = 16c + 8*h2 + j (j=0..7)
    s16x8 ahi[8], alo[8];
    {
        const bool ok = grow < M;
        const float* ap = A + (size_t)grow * 128 + 8 * h2;
        #pragma unroll
        for (int c = 0; c < 8; c++) {
            float ff[8];
            if (ok) {
                float4 f0 = *(const float4*)(ap + c * 16);
                float4 f1 = *(const float4*)(ap + c * 16 + 4);
                ff[0]=f0.x; ff[1]=f0.y; ff[2]=f0.z; ff[3]=f0.w;
                ff[4]=f1.x; ff[5]=f1.y; ff[6]=f1.z; ff[7]=f1.w;
            } else {
                #pragma unroll
                for (int j = 0; j < 8; j++) ff[j] = 0.f;
            }
            #pragma unroll
            for (int j = 0; j < 8; j++) {
                unsigned u = __float_as_uint(ff[j]);
                float rem = ff[j] - __uint_as_float(u & 0xffff0000u);
                ahi[c][j] = (short)(u >> 16);
                alo[c][j] = (short)(__float_as_uint(rem) >> 16);
            }
        }
    }
    __syncthreads();

    f32x16 acc[2];
    #pragma unroll
    for (int i = 0; i < 16; i++) { acc[0][i] = 0.f; acc[1][i] = 0.f; }

    #pragma unroll
    for (int ni = 0; ni < 2; ni++) {
        const int n = ni * 64 + wc * 32 + m;     // B col for this lane
        const int nbase = n * 128;
        #pragma unroll
        for (int c = 0; c < 8; c++) {
            int chunk8 = 2 * c + h2;
            int koff = ((chunk8 ^ (n & 15)) << 3);
            s16x8 bhi = *(const s16x8*)&Bsm[0][nbase + koff];
            s16x8 blo = *(const s16x8*)&Bsm[1][nbase + koff];
            acc[ni] = __builtin_amdgcn_mfma_f32_32x32x16_bf16(ahi[c], bhi, acc[ni], 0, 0, 0);
            acc[ni] = __builtin_amdgcn_mfma_f32_32x32x16_bf16(alo[c], bhi, acc[ni], 0, 0, 0);
            acc[ni] = __builtin_amdgcn_mfma_f32_32x32x16_bf16(ahi[c], blo, acc[ni], 0, 0, 0);
        }
    }

    __syncthreads();   // all waves done reading Bsm; reuse as htile
    unsigned short* htile = (unsigned short*)&Bsm[0][0];   // [64][128] bf16
    #pragma unroll
    for (int ni = 0; ni < 2; ni++) {
        const int colg = ni * 64 + wc * 32 + m;
        #pragma unroll
        for (int r = 0; r < 16; r++) {
            int row = wr * 32 + (r & 3) + 8 * (r >> 2) + 4 * h2;  // C/D m74/m101
            htile[row * 128 + colg] = (short)f2bf(acc[ni][r]);
        }
    }
    __syncthreads();

    // copy h tile out (coalesced) + logits: thread = (row r, head q)
    {
        const int r = t >> 2, q = t & 3;
        const int growr = bm + r;
        if (growr < M) {
            uint4 v0 = *(uint4*)&htile[r * 128 + q * 32];
            uint4 v1 = *(uint4*)&htile[r * 128 + q * 32 + 8];
            uint4 v2 = *(uint4*)&htile[r * 128 + q * 32 + 16];
            uint4 v3 = *(uint4*)&htile[r * 128 + q * 32 + 24];
            uint4* hg = (uint4*)(H + (size_t)growr * 128);
            hg[q * 4 + 0] = v0; hg[q * 4 + 1] = v1;
            hg[q * 4 + 2] = v2; hg[q * 4 + 3] = v3;
            unsigned uu[16] = {v0.x, v0.y, v0.z, v0.w, v1.x, v1.y, v1.z, v1.w,
                               v2.x, v2.y, v2.z, v2.w, v3.x, v3.y, v3.z, v3.w};
            float ps = 0.f, pd = 0.f;
            #pragma unroll
            for (int i = 0; i < 16; i++) {
                float2 f = bf2f(uu[i]);
                ps += f.x * attsm[q * 32 + 2 * i]       + f.y * attsm[q * 32 + 2 * i + 1];
                pd += f.x * attsm[128 + q * 32 + 2 * i] + f.y * attsm[128 + q * 32 + 2 * i + 1];
            }
            a_s[growr * NHEAD + q] = ps;
            a_d[growr * NHEAD + q] = pd;
        }
    }
}

// ------------------------------ CSR build ---------------------------------
__global__ __launch_bounds__(256) void bucket_hist(const int* __restrict__ dst, int E,
                                                   unsigned long long magic,
                                                   int* __restrict__ bcnt) {
    __shared__ int sh[NB];
    const int t = threadIdx.x;
    for (int i = t; i < NB; i += 256) sh[i] = 0;
    __syncthreads();
    for (int i = blockIdx.x * blockDim.x + t; i < E; i += gridDim.x * blockDim.x) {
        int b = (int)(((unsigned long long)(unsigned)dst[i] * magic) >> 40);
        atomicAdd(&sh[b], 1);
    }
    __syncthreads();
    for (int i = t; i < NB; i += 256)
        if (sh[i]) atomicAdd(&bcnt[i], sh[i]);
}

__global__ __launch_bounds__(256) void bucket_scan(const int* __restrict__ bcnt,
                                                   int* __restrict__ bbase,
                                                   int* __restrict__ bcursor,
                                                   int* __restrict__ row_ptr,
                                                   int N, int E) {
    __shared__ int wsum[4];
    const int t = threadIdx.x, lane = t & 63, wid = t >> 6;
    int v0 = bcnt[2 * t], v1 = bcnt[2 * t + 1];
    int s = v0 + v1, incl = s;
    #pragma unroll
    for (int o = 1; o < 64; o <<= 1) {
        int u = __shfl_up(incl, o, 64);
        if (lane >= o) incl += u;
    }
    if (lane == 63) wsum[wid] = incl;
    __syncthreads();
    if (t == 0) {
        int a = 0;
        #pragma unroll
        for (int i = 0; i < 4; i++) { int x = wsum[i]; wsum[i] = a; a += x; }
    }
    __syncthreads();
    int excl = wsum[wid] + incl - s;
    bbase[2 * t] = excl;          bcursor[2 * t] = excl;
    bbase[2 * t + 1] = excl + v0; bcursor[2 * t + 1] = excl + v0;
    if (t == 0) { bbase[NB] = E; row_ptr[N] = E; }
}

__global__ __launch_bounds__(256) void partition(const int* __restrict__ src,
                                                 const int* __restrict__ dst, int E,
                                                 unsigned long long magic,
                                                 int* __restrict__ bcursor,
                                                 int2* __restrict__ ebuf) {
    __shared__ int shc[NB];    // per-bucket count in this block
    __shared__ int shb[NB];    // reserved global base
    __shared__ int shcur[NB];  // local cursor
    const int t = threadIdx.x;
    for (int i = t; i < NB; i += 256) shc[i] = 0;
    __syncthreads();
    const int e0 = blockIdx.x * 4096;
    int myb[16], mys[16], myd[16];
    #pragma unroll
    for (int u = 0; u < 16; u++) {
        int i = e0 + u * 256 + t;
        if (i < E) {
            mys[u] = src[i];
            myd[u] = dst[i];
            int b = (int)(((unsigned long long)(unsigned)myd[u] * magic) >> 40);
            myb[u] = b;
            atomicAdd(&shc[b], 1);
        } else myb[u] = -1;
    }
    __syncthreads();
    for (int i = t; i < NB; i += 256) {
        int c = shc[i];
        shcur[i] = 0;
        if (c) shb[i] = atomicAdd(&bcursor[i], c);
    }
    __syncthreads();
    #pragma unroll
    for (int u = 0; u < 16; u++) {
        if (myb[u] >= 0) {
            int o = atomicAdd(&shcur[myb[u]], 1);
            ebuf[shb[myb[u]] + o] = make_int2(mys[u], myd[u]);
        }
    }
}

__global__ __launch_bounds__(256) void build_bucket(const int2* __restrict__ ebuf,
                                                    const int* __restrict__ bbase,
                                                    int npb, int N,
                                                    int* __restrict__ row_ptr,
                                                    int* __restrict__ col) {
    __shared__ int degl[256];
    __shared__ int curl[256];
    const int b = blockIdx.x;
    const int t = threadIdx.x, lane = t & 63, wid = t >> 6;
    const int base = bbase[b];
    const int cnt = bbase[b + 1] - base;
    const int node0 = b * npb;
    for (int i = t; i < npb; i += 256) degl[i] = 0;
    __syncthreads();
    for (int i = t; i < cnt; i += 256) {
        int d = ebuf[base + i].y;
        atomicAdd(&degl[d - node0], 1);
    }
    __syncthreads();
    if (wid == 0) {
        int run = 0;
        for (int c = 0; c * 64 < npb; c++) {
            int idx = c * 64 + lane;
            int v = (idx < npb) ? degl[idx] : 0;
            int incl = v;
            #pragma unroll
            for (int o = 1; o < 64; o <<= 1) {
                int u = __shfl_up(incl, o, 64);
                if (lane >= o) incl += u;
            }
            int excl = incl - v + run;
            if (idx < npb) {
                curl[idx] = excl;
                int node = node0 + idx;
                if (node < N) row_ptr[node] = base + excl;
            }
            run += __shfl(incl, 63, 64);
        }
    }
    __syncthreads();
    for (int i = t; i < cnt; i += 256) {
        int2 ed = ebuf[base + i];
        int p = atomicAdd(&curl[ed.y - node0], 1);
        col[base + p] = ed.x;
    }
}

// ------------- gather aggregation: softmax-weighted sum per dst ------------
// 1 wave per dst node; lane c handles features 2c,2c+1 (one uint bf16x2 load
// -> a full 256B h row is a single wave transaction). head = c>>4.
__global__ __launch_bounds__(64) void aggregate(const unsigned short* __restrict__ h,
                                                const float* __restrict__ a_s,
                                                const float* __restrict__ a_d,
                                                const int* __restrict__ row_ptr,
                                                const int* __restrict__ col,
                                                const float* __restrict__ bias,
                                                float* __restrict__ out,
                                                float* __restrict__ out2,
                                                int n, int do_relu) {
    const int nid = blockIdx.x;
    const int c = threadIdx.x;          // 0..63
    const int hd = c >> 4;
    const float ad = a_d[nid * NHEAD + hd];
    const unsigned* __restrict__ h2 = (const unsigned*)h;

    float e = a_s[nid * NHEAD + hd] + ad;        // self loop
    e = (e > 0.f) ? e : 0.2f * e;
    float den = __expf(e);
    float2 hv = bf2f(h2[(size_t)nid * 64 + c]);
    float num0 = den * hv.x, num1 = den * hv.y;

    const int beg = row_ptr[nid], end = row_ptr[nid + 1];
    int j = beg;
    for (; j + 8 <= end; j += 8) {
        int s[8];
        #pragma unroll
        for (int u = 0; u < 8; u++) s[u] = col[j + u];
        unsigned v[8]; float el[8];
        #pragma unroll
        for (int u = 0; u < 8; u++) v[u] = h2[(size_t)s[u] * 64 + c];
        #pragma unroll
        for (int u = 0; u < 8; u++) el[u] = a_s[s[u] * NHEAD + hd];
        #pragma unroll
        for (int u = 0; u < 8; u++) {
            float e2 = el[u] + ad;
            e2 = (e2 > 0.f) ? e2 : 0.2f * e2;
            float wgt = __expf(e2);
            den += wgt;
            float2 f = bf2f(v[u]);
            num0 += wgt * f.x;
            num1 += wgt * f.y;
        }
    }
    for (; j < end; j++) {
        int s = col[j];
        float e2 = a_s[s * NHEAD + hd] + ad;
        e2 = (e2 > 0.f) ? e2 : 0.2f * e2;
        float wgt = __expf(e2);
        den += wgt;
        float2 f = bf2f(h2[(size_t)s * 64 + c]);
        num0 += wgt * f.x;
        num1 += wgt * f.y;
    }
    float2 bv = ((const float2*)bias)[c];
    float rd = 1.0f / den;
    float o0 = num0 * rd + bv.x;
    float o1 = num1 * rd + bv.y;
    if (do_relu) { o0 = fmaxf(o0, 0.f); o1 = fmaxf(o1, 0.f); }
    ((float2*)out)[(size_t)nid * 64 + c] = make_float2(o0, o1);
    if (out2) ((float2*)out2)[(size_t)nid * 64 + c] = make_float2(o0, o1);
}

// ------------------------------- launcher ----------------------------------
extern "C" void kernel_launch(void* const* d_in, const int* in_sizes, int n_in,
                              void* d_out, int out_size, void* d_ws, size_t ws_size,
                              hipStream_t stream) {
    const float* x        = (const float*)d_in[0];
    const int*   edge     = (const int*)d_in[1];
    const float* W1       = (const float*)d_in[2];
    const float* att_s1   = (const float*)d_in[3];
    const float* att_d1   = (const float*)d_in[4];
    const float* b1       = (const float*)d_in[5];
    const float* W2       = (const float*)d_in[6];
    const float* att_s2   = (const float*)d_in[7];
    const float* att_d2   = (const float*)d_in[8];
    const float* b2       = (const float*)d_in[9];
    float* out = (float*)d_out;

    const int N = in_sizes[0] / FDIM;         // 50000
    const int E = in_sizes[1] / 2;            // 1600000
    const int* src = edge;
    const int* dst = edge + E;

    const int npb = (N + NB - 1) / NB;        // 98
    const unsigned long long magic = ((1ull << 40) / (unsigned long long)npb) + 1;

    char* w = (char*)d_ws;
    size_t off = 0;
    auto alloc = [&](size_t bytes) { void* p = w + off; off = (off + bytes + 255) & ~(size_t)255; return p; };
    int*   row_ptr = (int*)alloc((size_t)(N + 1) * 4);
    int*   col     = (int*)alloc((size_t)E * 4);
    int*   bcnt    = (int*)alloc((size_t)NB * 4);
    int*   bbase   = (int*)alloc((size_t)(NB + 1) * 4);
    int*   bcursor = (int*)alloc((size_t)NB * 4);
    unsigned short* h1 = (unsigned short*)alloc((size_t)N * FDIM * 2);  // bf16
    float* hx      = (float*)alloc((size_t)N * FDIM * 4);   // layer-1 out; ebuf alias
    float* as1     = (float*)alloc((size_t)N * NHEAD * 4);
    float* ad1     = (float*)alloc((size_t)N * NHEAD * 4);
    float* as2     = (float*)alloc((size_t)N * NHEAD * 4);
    float* ad2     = (float*)alloc((size_t)N * NHEAD * 4);
    short* Bg1hi   = (short*)alloc((size_t)128 * 128 * 2);
    short* Bg1lo   = (short*)alloc((size_t)128 * 128 * 2);
    short* Bg2hi   = (short*)alloc((size_t)128 * 128 * 2);
    short* Bg2lo   = (short*)alloc((size_t)128 * 128 * 2);
    int2*  ebuf    = (int2*)hx;   // dead before aggregate-1 writes hx
    (void)ws_size;

    // ---- weight prep (both layers) ----
    prep_w<<<1, 256, 0, stream>>>(W1, Bg1hi, Bg1lo);
    prep_w<<<1, 256, 0, stream>>>(W2, Bg2hi, Bg2lo);

    // ---- CSR build (bucketed; shared by both layers) ----
    hipMemsetAsync(bcnt, 0, (size_t)NB * 4, stream);
    bucket_hist<<<1024, 256, 0, stream>>>(dst, E, magic, bcnt);
    bucket_scan<<<1, 256, 0, stream>>>(bcnt, bbase, bcursor, row_ptr, N, E);
    partition<<<(E + 4095) / 4096, 256, 0, stream>>>(src, dst, E, magic, bcursor, ebuf);
    build_bucket<<<NB, 256, 0, stream>>>(ebuf, bbase, npb, N, row_ptr, col);

    const int gblocks = (N + 63) / 64;

    // ---- layer 1 ----
    gemm_mfma<<<gblocks, 256, 0, stream>>>(x, Bg1hi, Bg1lo, h1, att_s1, att_d1, as1, ad1, N);
    aggregate<<<N, 64, 0, stream>>>(h1, as1, ad1, row_ptr, col, b1, hx, nullptr, N, 1);

    // ---- layer 2 ----
    gemm_mfma<<<gblocks, 256, 0, stream>>>(hx, Bg2hi, Bg2lo, h1, att_s2, att_d2, as2, ad2, N);
    aggregate<<<N, 64, 0, stream>>>(h1, as2, ad2, row_ptr, col, b2,
                                    out, out + (size_t)N * FDIM, N, 0);
}

// Round 6
// 338.112 us; speedup vs baseline: 2.3811x; 1.0310x over previous
//
#include <hip/hip_runtime.h>
#include <hip/hip_bf16.h>

// GAT, 2 layers. N=50000, F=128, H=4, C=32, E=1.6M (+N self-loops).
// R6: (1) prep_w grid-parallel + merged with bucket_hist (was 2 serial
// single-block launches ~40us); (2) per-(edge,head) softmax weights
// precomputed by edge_w (full lane utilization; a_s table L2-resident)
// -> aggregate inner loop drops exp/lrelu (~40% VALU cut); (3) lrelu as
// fmax(x,0.2x). GEMM: split-bf16 MFMA (R5). CSR: bucket partition (R3).

#define FDIM 128
#define NHEAD 4
#define NB 512          // dst buckets for CSR build

typedef __attribute__((ext_vector_type(16))) float f32x16;
typedef __attribute__((ext_vector_type(8)))  short s16x8;

__device__ inline unsigned short f2bf(float f) {
    union { float f; unsigned u; } v; v.f = f;
    unsigned r = v.u + 0x7fff + ((v.u >> 16) & 1);   // RNE
    return (unsigned short)(r >> 16);
}
__device__ inline float2 bf2f(unsigned v) {
    union { unsigned u; float f; } a, b;
    a.u = v << 16;            // low half  = feature 2c
    b.u = v & 0xffff0000u;    // high half = feature 2c+1
    return make_float2(a.f, b.f);
}
__device__ inline void splitbf(float f, short* hi, short* lo) {
    unsigned u = __float_as_uint(f);
    float rem = f - __uint_as_float(u & 0xffff0000u);
    *hi = (short)(u >> 16);
    *lo = (short)(__float_as_uint(rem) >> 16);
}

// ---- fused: prep W1/W2 (transpose+split+swizzle) + bucket histogram ------
// blocks 0..63: W1, 64..127: W2, 128..: hist.
// W layout: out[n*128 + ((k>>3)^(n&15))*8 + (k&7)], hi/lo split bf16.
__global__ __launch_bounds__(256) void prep_hist(const float* __restrict__ W1,
                                                 short* __restrict__ B1hi,
                                                 short* __restrict__ B1lo,
                                                 const float* __restrict__ W2,
                                                 short* __restrict__ B2hi,
                                                 short* __restrict__ B2lo,
                                                 const int* __restrict__ dst, int E,
                                                 unsigned long long magic,
                                                 int* __restrict__ bcnt) {
    __shared__ int sh[NB];
    const int t = threadIdx.x;
    const int b = blockIdx.x;
    if (b < 128) {
        const float* W = (b < 64) ? W1 : W2;
        short* Bhi = (b < 64) ? B1hi : B2hi;
        short* Blo = (b < 64) ? B1lo : B2lo;
        int e = (b & 63) * 256 + t;   // e = k*128 + n
        int k = e >> 7, n = e & 127;
        short hi, lo;
        splitbf(W[e], &hi, &lo);
        int idx = n * 128 + (((k >> 3) ^ (n & 15)) << 3) + (k & 7);
        Bhi[idx] = hi;
        Blo[idx] = lo;
        return;
    }
    for (int i = t; i < NB; i += 256) sh[i] = 0;
    __syncthreads();
    const int stride = (gridDim.x - 128) * 256;
    for (int i = (b - 128) * 256 + t; i < E; i += stride) {
        int bk = (int)(((unsigned long long)(unsigned)dst[i] * magic) >> 40);
        atomicAdd(&sh[bk], 1);
    }
    __syncthreads();
    for (int i = t; i < NB; i += 256)
        if (sh[i]) atomicAdd(&bcnt[i], sh[i]);
}

// ---- MFMA GEMM: H[M][128](bf16) = A[M][128](f32) @ W; fused a_s/a_d ------
__global__ __launch_bounds__(256) void gemm_mfma(const float* __restrict__ A,
                                                 const short* __restrict__ Bghi,
                                                 const short* __restrict__ Bglo,
                                                 unsigned short* __restrict__ H,
                                                 const float* __restrict__ att_s,
                                                 const float* __restrict__ att_d,
                                                 float* __restrict__ a_s,
                                                 float* __restrict__ a_d, int M) {
    __shared__ short Bsm[2][16384];   // 64 KB: [hi/lo][n*128 + k']
    __shared__ float attsm[256];      // att_s[128], att_d[128]
    const int t = threadIdx.x;
    const int bm = blockIdx.x * 64;

    if (t < 128) attsm[t] = att_s[t];
    else         attsm[t] = att_d[t - 128];

    {   // stage B (pre-swizzled; verbatim 32KB+32KB copy)
        const uint4* ghi = (const uint4*)Bghi;
        const uint4* glo = (const uint4*)Bglo;
        uint4* shi = (uint4*)&Bsm[0][0];
        uint4* slo = (uint4*)&Bsm[1][0];
        #pragma unroll
        for (int i = 0; i < 8; i++) {
            shi[t + i * 256] = ghi[t + i * 256];
            slo[t + i * 256] = glo[t + i * 256];
        }
    }

    const int lane = t & 63;
    const int w = t >> 6;
    const int wr = w >> 1, wc = w & 1;     // wave tile: rows wr*32, cols wc*32
    const int m  = lane & 31, h2 = lane >> 5;
    const int grow = bm + wr * 32 + m;

    // A fragments: 8 k-chunks of 16; lane holds k = 16c + 8*h2 + j (j=0..7)
    s16x8 ahi[8], alo[8];
    {
        const bool ok = grow < M;
        const float* ap = A + (size_t)grow * 128 + 8 * h2;
        #pragma unroll
        for (int c = 0; c < 8; c++) {
            float ff[8];
            if (ok) {
                float4 f0 = *(const float4*)(ap + c * 16);
                float4 f1 = *(const float4*)(ap + c * 16 + 4);
                ff[0]=f0.x; ff[1]=f0.y; ff[2]=f0.z; ff[3]=f0.w;
                ff[4]=f1.x; ff[5]=f1.y; ff[6]=f1.z; ff[7]=f1.w;
            } else {
                #pragma unroll
                for (int j = 0; j < 8; j++) ff[j] = 0.f;
            }
            #pragma unroll
            for (int j = 0; j < 8; j++) {
                short hi, lo;
                splitbf(ff[j], &hi, &lo);
                ahi[c][j] = hi;
                alo[c][j] = lo;
            }
        }
    }
    __syncthreads();

    f32x16 acc[2];
    #pragma unroll
    for (int i = 0; i < 16; i++) { acc[0][i] = 0.f; acc[1][i] = 0.f; }

    #pragma unroll
    for (int ni = 0; ni < 2; ni++) {
        const int n = ni * 64 + wc * 32 + m;     // B col for this lane
        const int nbase = n * 128;
        #pragma unroll
        for (int c = 0; c < 8; c++) {
            int chunk8 = 2 * c + h2;
            int koff = ((chunk8 ^ (n & 15)) << 3);
            s16x8 bhi = *(const s16x8*)&Bsm[0][nbase + koff];
            s16x8 blo = *(const s16x8*)&Bsm[1][nbase + koff];
            acc[ni] = __builtin_amdgcn_mfma_f32_32x32x16_bf16(ahi[c], bhi, acc[ni], 0, 0, 0);
            acc[ni] = __builtin_amdgcn_mfma_f32_32x32x16_bf16(alo[c], bhi, acc[ni], 0, 0, 0);
            acc[ni] = __builtin_amdgcn_mfma_f32_32x32x16_bf16(ahi[c], blo, acc[ni], 0, 0, 0);
        }
    }

    __syncthreads();   // all waves done reading Bsm; reuse as htile
    unsigned short* htile = (unsigned short*)&Bsm[0][0];   // [64][128] bf16
    #pragma unroll
    for (int ni = 0; ni < 2; ni++) {
        const int colg = ni * 64 + wc * 32 + m;
        #pragma unroll
        for (int r = 0; r < 16; r++) {
            int row = wr * 32 + (r & 3) + 8 * (r >> 2) + 4 * h2;  // C/D m74/m101
            htile[row * 128 + colg] = (short)f2bf(acc[ni][r]);
        }
    }
    __syncthreads();

    // copy h tile out (coalesced) + logits: thread = (row r, head q)
    {
        const int r = t >> 2, q = t & 3;
        const int growr = bm + r;
        if (growr < M) {
            uint4 v0 = *(uint4*)&htile[r * 128 + q * 32];
            uint4 v1 = *(uint4*)&htile[r * 128 + q * 32 + 8];
            uint4 v2 = *(uint4*)&htile[r * 128 + q * 32 + 16];
            uint4 v3 = *(uint4*)&htile[r * 128 + q * 32 + 24];
            uint4* hg = (uint4*)(H + (size_t)growr * 128);
            hg[q * 4 + 0] = v0; hg[q * 4 + 1] = v1;
            hg[q * 4 + 2] = v2; hg[q * 4 + 3] = v3;
            unsigned uu[16] = {v0.x, v0.y, v0.z, v0.w, v1.x, v1.y, v1.z, v1.w,
                               v2.x, v2.y, v2.z, v2.w, v3.x, v3.y, v3.z, v3.w};
            float ps = 0.f, pd = 0.f;
            #pragma unroll
            for (int i = 0; i < 16; i++) {
                float2 f = bf2f(uu[i]);
                ps += f.x * attsm[q * 32 + 2 * i]       + f.y * attsm[q * 32 + 2 * i + 1];
                pd += f.x * attsm[128 + q * 32 + 2 * i] + f.y * attsm[128 + q * 32 + 2 * i + 1];
            }
            a_s[growr * NHEAD + q] = ps;
            a_d[growr * NHEAD + q] = pd;
        }
    }
}

// ------------------------------ CSR build ---------------------------------
__global__ __launch_bounds__(256) void bucket_scan(const int* __restrict__ bcnt,
                                                   int* __restrict__ bbase,
                                                   int* __restrict__ bcursor,
                                                   int* __restrict__ row_ptr,
                                                   int N, int E) {
    __shared__ int wsum[4];
    const int t = threadIdx.x, lane = t & 63, wid = t >> 6;
    int v0 = bcnt[2 * t], v1 = bcnt[2 * t + 1];
    int s = v0 + v1, incl = s;
    #pragma unroll
    for (int o = 1; o < 64; o <<= 1) {
        int u = __shfl_up(incl, o, 64);
        if (lane >= o) incl += u;
    }
    if (lane == 63) wsum[wid] = incl;
    __syncthreads();
    if (t == 0) {
        int a = 0;
        #pragma unroll
        for (int i = 0; i < 4; i++) { int x = wsum[i]; wsum[i] = a; a += x; }
    }
    __syncthreads();
    int excl = wsum[wid] + incl - s;
    bbase[2 * t] = excl;          bcursor[2 * t] = excl;
    bbase[2 * t + 1] = excl + v0; bcursor[2 * t + 1] = excl + v0;
    if (t == 0) { bbase[NB] = E; row_ptr[N] = E; }
}

__global__ __launch_bounds__(256) void partition(const int* __restrict__ src,
                                                 const int* __restrict__ dst, int E,
                                                 unsigned long long magic,
                                                 int* __restrict__ bcursor,
                                                 int2* __restrict__ ebuf) {
    __shared__ int shc[NB];    // per-bucket count in this block
    __shared__ int shb[NB];    // reserved global base
    __shared__ int shcur[NB];  // local cursor
    const int t = threadIdx.x;
    for (int i = t; i < NB; i += 256) shc[i] = 0;
    __syncthreads();
    const int e0 = blockIdx.x * 4096;
    int myb[16], mys[16], myd[16];
    #pragma unroll
    for (int u = 0; u < 16; u++) {
        int i = e0 + u * 256 + t;
        if (i < E) {
            mys[u] = src[i];
            myd[u] = dst[i];
            int b = (int)(((unsigned long long)(unsigned)myd[u] * magic) >> 40);
            myb[u] = b;
            atomicAdd(&shc[b], 1);
        } else myb[u] = -1;
    }
    __syncthreads();
    for (int i = t; i < NB; i += 256) {
        int c = shc[i];
        shcur[i] = 0;
        if (c) shb[i] = atomicAdd(&bcursor[i], c);
    }
    __syncthreads();
    #pragma unroll
    for (int u = 0; u < 16; u++) {
        if (myb[u] >= 0) {
            int o = atomicAdd(&shcur[myb[u]], 1);
            ebuf[shb[myb[u]] + o] = make_int2(mys[u], myd[u]);
        }
    }
}

__global__ __launch_bounds__(256) void build_bucket(const int2* __restrict__ ebuf,
                                                    const int* __restrict__ bbase,
                                                    int npb, int N,
                                                    int* __restrict__ row_ptr,
                                                    int* __restrict__ col,
                                                    int* __restrict__ edst) {
    __shared__ int degl[256];
    __shared__ int curl[256];
    const int b = blockIdx.x;
    const int t = threadIdx.x, lane = t & 63, wid = t >> 6;
    const int base = bbase[b];
    const int cnt = bbase[b + 1] - base;
    const int node0 = b * npb;
    for (int i = t; i < npb; i += 256) degl[i] = 0;
    __syncthreads();
    for (int i = t; i < cnt; i += 256) {
        int d = ebuf[base + i].y;
        atomicAdd(&degl[d - node0], 1);
    }
    __syncthreads();
    if (wid == 0) {
        int run = 0;
        for (int c = 0; c * 64 < npb; c++) {
            int idx = c * 64 + lane;
            int v = (idx < npb) ? degl[idx] : 0;
            int incl = v;
            #pragma unroll
            for (int o = 1; o < 64; o <<= 1) {
                int u = __shfl_up(incl, o, 64);
                if (lane >= o) incl += u;
            }
            int excl = incl - v + run;
            if (idx < npb) {
                curl[idx] = excl;
                int node = node0 + idx;
                if (node < N) row_ptr[node] = base + excl;
            }
            run += __shfl(incl, 63, 64);
        }
    }
    __syncthreads();
    for (int i = t; i < cnt; i += 256) {
        int2 ed = ebuf[base + i];
        int p = atomicAdd(&curl[ed.y - node0], 1);
        col[base + p] = ed.x;
        edst[base + p] = ed.y;
    }
}

// ---- per-(edge,head) softmax weights: w4[e] = exp(lrelu(a_s[src]+a_d[dst]))
__global__ __launch_bounds__(256) void edge_w(const int* __restrict__ col,
                                              const int* __restrict__ edst,
                                              const float4* __restrict__ as4,
                                              const float4* __restrict__ ad4,
                                              int E, float4* __restrict__ w4) {
    int i = blockIdx.x * 256 + threadIdx.x;
    if (i >= E) return;
    float4 a = as4[col[i]];
    float4 b = ad4[edst[i]];
    float ex = a.x + b.x, ey = a.y + b.y, ez = a.z + b.z, ew = a.w + b.w;
    ex = fmaxf(ex, 0.2f * ex); ey = fmaxf(ey, 0.2f * ey);
    ez = fmaxf(ez, 0.2f * ez); ew = fmaxf(ew, 0.2f * ew);
    w4[i] = make_float4(__expf(ex), __expf(ey), __expf(ez), __expf(ew));
}

// ------------- gather aggregation: softmax-weighted sum per dst ------------
// 1 wave per dst node; lane c handles features 2c,2c+1. head = c>>4.
// weights precomputed by edge_w -> inner loop is pure gather+fma.
__global__ __launch_bounds__(64) void aggregate(const unsigned short* __restrict__ h,
                                                const float* __restrict__ a_s,
                                                const float* __restrict__ a_d,
                                                const int* __restrict__ row_ptr,
                                                const int* __restrict__ col,
                                                const float* __restrict__ wbuf,
                                                const float* __restrict__ bias,
                                                float* __restrict__ out,
                                                float* __restrict__ out2,
                                                int n, int do_relu) {
    const int nid = blockIdx.x;
    const int c = threadIdx.x;          // 0..63
    const int hd = c >> 4;
    const unsigned* __restrict__ h2 = (const unsigned*)h;

    // self loop (src = dst)
    float e = a_s[nid * NHEAD + hd] + a_d[nid * NHEAD + hd];
    e = fmaxf(e, 0.2f * e);
    float den = __expf(e);
    float2 hv = bf2f(h2[(size_t)nid * 64 + c]);
    float num0 = den * hv.x, num1 = den * hv.y;

    const int beg = row_ptr[nid], end = row_ptr[nid + 1];
    int j = beg;
    for (; j + 8 <= end; j += 8) {
        int s[8];
        #pragma unroll
        for (int u = 0; u < 8; u++) s[u] = col[j + u];
        unsigned v[8]; float wv[8];
        #pragma unroll
        for (int u = 0; u < 8; u++) v[u] = h2[(size_t)s[u] * 64 + c];
        #pragma unroll
        for (int u = 0; u < 8; u++) wv[u] = wbuf[(size_t)(j + u) * 4 + hd];
        #pragma unroll
        for (int u = 0; u < 8; u++) {
            den += wv[u];
            float2 f = bf2f(v[u]);
            num0 += wv[u] * f.x;
            num1 += wv[u] * f.y;
        }
    }
    for (; j < end; j++) {
        int s = col[j];
        float wgt = wbuf[(size_t)j * 4 + hd];
        den += wgt;
        float2 f = bf2f(h2[(size_t)s * 64 + c]);
        num0 += wgt * f.x;
        num1 += wgt * f.y;
    }
    float2 bv = ((const float2*)bias)[c];
    float rd = 1.0f / den;
    float o0 = num0 * rd + bv.x;
    float o1 = num1 * rd + bv.y;
    if (do_relu) { o0 = fmaxf(o0, 0.f); o1 = fmaxf(o1, 0.f); }
    ((float2*)out)[(size_t)nid * 64 + c] = make_float2(o0, o1);
    if (out2) ((float2*)out2)[(size_t)nid * 64 + c] = make_float2(o0, o1);
}

// ------------------------------- launcher ----------------------------------
extern "C" void kernel_launch(void* const* d_in, const int* in_sizes, int n_in,
                              void* d_out, int out_size, void* d_ws, size_t ws_size,
                              hipStream_t stream) {
    const float* x        = (const float*)d_in[0];
    const int*   edge     = (const int*)d_in[1];
    const float* W1       = (const float*)d_in[2];
    const float* att_s1   = (const float*)d_in[3];
    const float* att_d1   = (const float*)d_in[4];
    const float* b1       = (const float*)d_in[5];
    const float* W2       = (const float*)d_in[6];
    const float* att_s2   = (const float*)d_in[7];
    const float* att_d2   = (const float*)d_in[8];
    const float* b2       = (const float*)d_in[9];
    float* out = (float*)d_out;

    const int N = in_sizes[0] / FDIM;         // 50000
    const int E = in_sizes[1] / 2;            // 1600000
    const int* src = edge;
    const int* dst = edge + E;

    const int npb = (N + NB - 1) / NB;        // 98
    const unsigned long long magic = ((1ull << 40) / (unsigned long long)npb) + 1;

    char* w = (char*)d_ws;
    size_t off = 0;
    auto alloc = [&](size_t bytes) { void* p = w + off; off = (off + bytes + 255) & ~(size_t)255; return p; };
    int*   row_ptr = (int*)alloc((size_t)(N + 1) * 4);
    int*   col     = (int*)alloc((size_t)E * 4);
    int*   edst    = (int*)alloc((size_t)E * 4);
    float* wbuf    = (float*)alloc((size_t)E * 4 * 4);      // per-(edge,head) w
    int*   bcnt    = (int*)alloc((size_t)NB * 4);
    int*   bbase   = (int*)alloc((size_t)(NB + 1) * 4);
    int*   bcursor = (int*)alloc((size_t)NB * 4);
    unsigned short* h1 = (unsigned short*)alloc((size_t)N * FDIM * 2);  // bf16
    float* hx      = (float*)alloc((size_t)N * FDIM * 4);   // layer-1 out; ebuf alias
    float* as1     = (float*)alloc((size_t)N * NHEAD * 4);
    float* ad1     = (float*)alloc((size_t)N * NHEAD * 4);
    float* as2     = (float*)alloc((size_t)N * NHEAD * 4);
    float* ad2     = (float*)alloc((size_t)N * NHEAD * 4);
    short* Bg1hi   = (short*)alloc((size_t)128 * 128 * 2);
    short* Bg1lo   = (short*)alloc((size_t)128 * 128 * 2);
    short* Bg2hi   = (short*)alloc((size_t)128 * 128 * 2);
    short* Bg2lo   = (short*)alloc((size_t)128 * 128 * 2);
    int2*  ebuf    = (int2*)hx;   // dead before aggregate-1 writes hx
    (void)ws_size;

    // ---- fused weight-prep + bucket histogram ----
    hipMemsetAsync(bcnt, 0, (size_t)NB * 4, stream);
    prep_hist<<<128 + 1024, 256, 0, stream>>>(W1, Bg1hi, Bg1lo, W2, Bg2hi, Bg2lo,
                                              dst, E, magic, bcnt);
    bucket_scan<<<1, 256, 0, stream>>>(bcnt, bbase, bcursor, row_ptr, N, E);
    partition<<<(E + 4095) / 4096, 256, 0, stream>>>(src, dst, E, magic, bcursor, ebuf);
    build_bucket<<<NB, 256, 0, stream>>>(ebuf, bbase, npb, N, row_ptr, col, edst);

    const int gblocks = (N + 63) / 64;
    const int eb = (E + 255) / 256;

    // ---- layer 1 ----
    gemm_mfma<<<gblocks, 256, 0, stream>>>(x, Bg1hi, Bg1lo, h1, att_s1, att_d1, as1, ad1, N);
    edge_w<<<eb, 256, 0, stream>>>(col, edst, (const float4*)as1, (const float4*)ad1,
                                   E, (float4*)wbuf);
    aggregate<<<N, 64, 0, stream>>>(h1, as1, ad1, row_ptr, col, wbuf, b1,
                                    hx, nullptr, N, 1);

    // ---- layer 2 ----
    gemm_mfma<<<gblocks, 256, 0, stream>>>(hx, Bg2hi, Bg2lo, h1, att_s2, att_d2, as2, ad2, N);
    edge_w<<<eb, 256, 0, stream>>>(col, edst, (const float4*)as2, (const float4*)ad2,
                                   E, (float4*)wbuf);
    aggregate<<<N, 64, 0, stream>>>(h1, as2, ad2, row_ptr, col, wbuf, b2,
                                    out, out + (size_t)N * FDIM, N, 0);
}

// Round 7
// 337.980 us; speedup vs baseline: 2.3820x; 1.0004x over previous
//
#include <hip/hip_runtime.h>
#include <hip/hip_bf16.h>
#include <hip/hip_fp16.h>

// GAT, 2 layers. N=50000, F=128, H=4, C=32, E=1.6M (+N self-loops).
// R7: h split into head-pair halves h0/h1 (6.4MB each); aggregate block
// parity selects the half -> with round-robin blockIdx->XCD dispatch each
// XCD's L2 only sees one 6.4MB half (was 12.8MB, 40% miss). Edge weights
// fp16 half2 per pair (read 25.6->6.4MB/pass). 1 wave = 2 nodes x 32 lanes.
// GEMM: split-bf16 MFMA (R5). CSR: bucket partition (R3). edge_w fp16.

#define FDIM 128
#define NHEAD 4
#define NB 512          // dst buckets for CSR build

typedef __attribute__((ext_vector_type(16))) float f32x16;
typedef __attribute__((ext_vector_type(8)))  short s16x8;

__device__ inline unsigned short f2bf(float f) {
    union { float f; unsigned u; } v; v.f = f;
    unsigned r = v.u + 0x7fff + ((v.u >> 16) & 1);   // RNE
    return (unsigned short)(r >> 16);
}
__device__ inline float2 bf2f(unsigned v) {
    union { unsigned u; float f; } a, b;
    a.u = v << 16;            // low half  = feature 2c
    b.u = v & 0xffff0000u;    // high half = feature 2c+1
    return make_float2(a.f, b.f);
}
__device__ inline void splitbf(float f, short* hi, short* lo) {
    unsigned u = __float_as_uint(f);
    float rem = f - __uint_as_float(u & 0xffff0000u);
    *hi = (short)(u >> 16);
    *lo = (short)(__float_as_uint(rem) >> 16);
}

// ---- fused: prep W1/W2 (transpose+split+swizzle) + bucket histogram ------
__global__ __launch_bounds__(256) void prep_hist(const float* __restrict__ W1,
                                                 short* __restrict__ B1hi,
                                                 short* __restrict__ B1lo,
                                                 const float* __restrict__ W2,
                                                 short* __restrict__ B2hi,
                                                 short* __restrict__ B2lo,
                                                 const int* __restrict__ dst, int E,
                                                 unsigned long long magic,
                                                 int* __restrict__ bcnt) {
    __shared__ int sh[NB];
    const int t = threadIdx.x;
    const int b = blockIdx.x;
    if (b < 128) {
        const float* W = (b < 64) ? W1 : W2;
        short* Bhi = (b < 64) ? B1hi : B2hi;
        short* Blo = (b < 64) ? B1lo : B2lo;
        int e = (b & 63) * 256 + t;   // e = k*128 + n
        int k = e >> 7, n = e & 127;
        short hi, lo;
        splitbf(W[e], &hi, &lo);
        int idx = n * 128 + (((k >> 3) ^ (n & 15)) << 3) + (k & 7);
        Bhi[idx] = hi;
        Blo[idx] = lo;
        return;
    }
    for (int i = t; i < NB; i += 256) sh[i] = 0;
    __syncthreads();
    const int stride = (gridDim.x - 128) * 256;
    for (int i = (b - 128) * 256 + t; i < E; i += stride) {
        int bk = (int)(((unsigned long long)(unsigned)dst[i] * magic) >> 40);
        atomicAdd(&sh[bk], 1);
    }
    __syncthreads();
    for (int i = t; i < NB; i += 256)
        if (sh[i]) atomicAdd(&bcnt[i], sh[i]);
}

// ---- MFMA GEMM: H0/H1[M][64](bf16) = A[M][128](f32) @ W; fused a_s/a_d ---
__global__ __launch_bounds__(256) void gemm_mfma(const float* __restrict__ A,
                                                 const short* __restrict__ Bghi,
                                                 const short* __restrict__ Bglo,
                                                 unsigned short* __restrict__ H0,
                                                 unsigned short* __restrict__ H1,
                                                 const float* __restrict__ att_s,
                                                 const float* __restrict__ att_d,
                                                 float* __restrict__ a_s,
                                                 float* __restrict__ a_d, int M) {
    __shared__ short Bsm[2][16384];   // 64 KB: [hi/lo][n*128 + k']
    __shared__ float attsm[256];      // att_s[128], att_d[128]
    const int t = threadIdx.x;
    const int bm = blockIdx.x * 64;

    if (t < 128) attsm[t] = att_s[t];
    else         attsm[t] = att_d[t - 128];

    {   // stage B (pre-swizzled; verbatim 32KB+32KB copy)
        const uint4* ghi = (const uint4*)Bghi;
        const uint4* glo = (const uint4*)Bglo;
        uint4* shi = (uint4*)&Bsm[0][0];
        uint4* slo = (uint4*)&Bsm[1][0];
        #pragma unroll
        for (int i = 0; i < 8; i++) {
            shi[t + i * 256] = ghi[t + i * 256];
            slo[t + i * 256] = glo[t + i * 256];
        }
    }

    const int lane = t & 63;
    const int w = t >> 6;
    const int wr = w >> 1, wc = w & 1;     // wave tile: rows wr*32, cols wc*32
    const int m  = lane & 31, h2 = lane >> 5;
    const int grow = bm + wr * 32 + m;

    // A fragments: 8 k-chunks of 16; lane holds k = 16c + 8*h2 + j (j=0..7)
    s16x8 ahi[8], alo[8];
    {
        const bool ok = grow < M;
        const float* ap = A + (size_t)grow * 128 + 8 * h2;
        #pragma unroll
        for (int c = 0; c < 8; c++) {
            float ff[8];
            if (ok) {
                float4 f0 = *(const float4*)(ap + c * 16);
                float4 f1 = *(const float4*)(ap + c * 16 + 4);
                ff[0]=f0.x; ff[1]=f0.y; ff[2]=f0.z; ff[3]=f0.w;
                ff[4]=f1.x; ff[5]=f1.y; ff[6]=f1.z; ff[7]=f1.w;
            } else {
                #pragma unroll
                for (int j = 0; j < 8; j++) ff[j] = 0.f;
            }
            #pragma unroll
            for (int j = 0; j < 8; j++) {
                short hi, lo;
                splitbf(ff[j], &hi, &lo);
                ahi[c][j] = hi;
                alo[c][j] = lo;
            }
        }
    }
    __syncthreads();

    f32x16 acc[2];
    #pragma unroll
    for (int i = 0; i < 16; i++) { acc[0][i] = 0.f; acc[1][i] = 0.f; }

    #pragma unroll
    for (int ni = 0; ni < 2; ni++) {
        const int n = ni * 64 + wc * 32 + m;     // B col for this lane
        const int nbase = n * 128;
        #pragma unroll
        for (int c = 0; c < 8; c++) {
            int chunk8 = 2 * c + h2;
            int koff = ((chunk8 ^ (n & 15)) << 3);
            s16x8 bhi = *(const s16x8*)&Bsm[0][nbase + koff];
            s16x8 blo = *(const s16x8*)&Bsm[1][nbase + koff];
            acc[ni] = __builtin_amdgcn_mfma_f32_32x32x16_bf16(ahi[c], bhi, acc[ni], 0, 0, 0);
            acc[ni] = __builtin_amdgcn_mfma_f32_32x32x16_bf16(alo[c], bhi, acc[ni], 0, 0, 0);
            acc[ni] = __builtin_amdgcn_mfma_f32_32x32x16_bf16(ahi[c], blo, acc[ni], 0, 0, 0);
        }
    }

    __syncthreads();   // all waves done reading Bsm; reuse as htile
    unsigned short* htile = (unsigned short*)&Bsm[0][0];   // [64][128] bf16
    #pragma unroll
    for (int ni = 0; ni < 2; ni++) {
        const int colg = ni * 64 + wc * 32 + m;
        #pragma unroll
        for (int r = 0; r < 16; r++) {
            int row = wr * 32 + (r & 3) + 8 * (r >> 2) + 4 * h2;  // C/D m74/m101
            htile[row * 128 + colg] = (short)f2bf(acc[ni][r]);
        }
    }
    __syncthreads();

    // copy h tile out (split by head pair) + logits: thread = (row r, head q)
    {
        const int r = t >> 2, q = t & 3;
        const int growr = bm + r;
        if (growr < M) {
            uint4 v0 = *(uint4*)&htile[r * 128 + q * 32];
            uint4 v1 = *(uint4*)&htile[r * 128 + q * 32 + 8];
            uint4 v2 = *(uint4*)&htile[r * 128 + q * 32 + 16];
            uint4 v3 = *(uint4*)&htile[r * 128 + q * 32 + 24];
            unsigned short* Hp = (q < 2) ? H0 : H1;
            uint4* hg = (uint4*)(Hp + (size_t)growr * 64);
            const int qq = q & 1;
            hg[qq * 4 + 0] = v0; hg[qq * 4 + 1] = v1;
            hg[qq * 4 + 2] = v2; hg[qq * 4 + 3] = v3;
            unsigned uu[16] = {v0.x, v0.y, v0.z, v0.w, v1.x, v1.y, v1.z, v1.w,
                               v2.x, v2.y, v2.z, v2.w, v3.x, v3.y, v3.z, v3.w};
            float ps = 0.f, pd = 0.f;
            #pragma unroll
            for (int i = 0; i < 16; i++) {
                float2 f = bf2f(uu[i]);
                ps += f.x * attsm[q * 32 + 2 * i]       + f.y * attsm[q * 32 + 2 * i + 1];
                pd += f.x * attsm[128 + q * 32 + 2 * i] + f.y * attsm[128 + q * 32 + 2 * i + 1];
            }
            a_s[growr * NHEAD + q] = ps;
            a_d[growr * NHEAD + q] = pd;
        }
    }
}

// ------------------------------ CSR build ---------------------------------
__global__ __launch_bounds__(256) void bucket_scan(const int* __restrict__ bcnt,
                                                   int* __restrict__ bbase,
                                                   int* __restrict__ bcursor,
                                                   int* __restrict__ row_ptr,
                                                   int N, int E) {
    __shared__ int wsum[4];
    const int t = threadIdx.x, lane = t & 63, wid = t >> 6;
    int v0 = bcnt[2 * t], v1 = bcnt[2 * t + 1];
    int s = v0 + v1, incl = s;
    #pragma unroll
    for (int o = 1; o < 64; o <<= 1) {
        int u = __shfl_up(incl, o, 64);
        if (lane >= o) incl += u;
    }
    if (lane == 63) wsum[wid] = incl;
    __syncthreads();
    if (t == 0) {
        int a = 0;
        #pragma unroll
        for (int i = 0; i < 4; i++) { int x = wsum[i]; wsum[i] = a; a += x; }
    }
    __syncthreads();
    int excl = wsum[wid] + incl - s;
    bbase[2 * t] = excl;          bcursor[2 * t] = excl;
    bbase[2 * t + 1] = excl + v0; bcursor[2 * t + 1] = excl + v0;
    if (t == 0) { bbase[NB] = E; row_ptr[N] = E; }
}

__global__ __launch_bounds__(256) void partition(const int* __restrict__ src,
                                                 const int* __restrict__ dst, int E,
                                                 unsigned long long magic,
                                                 int* __restrict__ bcursor,
                                                 int2* __restrict__ ebuf) {
    __shared__ int shc[NB];    // per-bucket count in this block
    __shared__ int shb[NB];    // reserved global base
    __shared__ int shcur[NB];  // local cursor
    const int t = threadIdx.x;
    for (int i = t; i < NB; i += 256) shc[i] = 0;
    __syncthreads();
    const int e0 = blockIdx.x * 4096;
    int myb[16], mys[16], myd[16];
    #pragma unroll
    for (int u = 0; u < 16; u++) {
        int i = e0 + u * 256 + t;
        if (i < E) {
            mys[u] = src[i];
            myd[u] = dst[i];
            int b = (int)(((unsigned long long)(unsigned)myd[u] * magic) >> 40);
            myb[u] = b;
            atomicAdd(&shc[b], 1);
        } else myb[u] = -1;
    }
    __syncthreads();
    for (int i = t; i < NB; i += 256) {
        int c = shc[i];
        shcur[i] = 0;
        if (c) shb[i] = atomicAdd(&bcursor[i], c);
    }
    __syncthreads();
    #pragma unroll
    for (int u = 0; u < 16; u++) {
        if (myb[u] >= 0) {
            int o = atomicAdd(&shcur[myb[u]], 1);
            ebuf[shb[myb[u]] + o] = make_int2(mys[u], myd[u]);
        }
    }
}

__global__ __launch_bounds__(256) void build_bucket(const int2* __restrict__ ebuf,
                                                    const int* __restrict__ bbase,
                                                    int npb, int N,
                                                    int* __restrict__ row_ptr,
                                                    int* __restrict__ col,
                                                    int* __restrict__ edst) {
    __shared__ int degl[256];
    __shared__ int curl[256];
    const int b = blockIdx.x;
    const int t = threadIdx.x, lane = t & 63, wid = t >> 6;
    const int base = bbase[b];
    const int cnt = bbase[b + 1] - base;
    const int node0 = b * npb;
    for (int i = t; i < npb; i += 256) degl[i] = 0;
    __syncthreads();
    for (int i = t; i < cnt; i += 256) {
        int d = ebuf[base + i].y;
        atomicAdd(&degl[d - node0], 1);
    }
    __syncthreads();
    if (wid == 0) {
        int run = 0;
        for (int c = 0; c * 64 < npb; c++) {
            int idx = c * 64 + lane;
            int v = (idx < npb) ? degl[idx] : 0;
            int incl = v;
            #pragma unroll
            for (int o = 1; o < 64; o <<= 1) {
                int u = __shfl_up(incl, o, 64);
                if (lane >= o) incl += u;
            }
            int excl = incl - v + run;
            if (idx < npb) {
                curl[idx] = excl;
                int node = node0 + idx;
                if (node < N) row_ptr[node] = base + excl;
            }
            run += __shfl(incl, 63, 64);
        }
    }
    __syncthreads();
    for (int i = t; i < cnt; i += 256) {
        int2 ed = ebuf[base + i];
        int p = atomicAdd(&curl[ed.y - node0], 1);
        col[base + p] = ed.x;
        edst[base + p] = ed.y;
    }
}

// ---- per-(edge,head) softmax weights, fp16, split by head pair -----------
__global__ __launch_bounds__(256) void edge_w(const int* __restrict__ col,
                                              const int* __restrict__ edst,
                                              const float4* __restrict__ as4,
                                              const float4* __restrict__ ad4,
                                              int E,
                                              __half2* __restrict__ w0,
                                              __half2* __restrict__ w1) {
    int i = blockIdx.x * 256 + threadIdx.x;
    if (i >= E) return;
    float4 a = as4[col[i]];
    float4 b = ad4[edst[i]];
    float ex = a.x + b.x, ey = a.y + b.y, ez = a.z + b.z, ew = a.w + b.w;
    ex = fmaxf(ex, 0.2f * ex); ey = fmaxf(ey, 0.2f * ey);
    ez = fmaxf(ez, 0.2f * ez); ew = fmaxf(ew, 0.2f * ew);
    w0[i] = __floats2half2_rn(__expf(ex), __expf(ey));
    w1[i] = __floats2half2_rn(__expf(ez), __expf(ew));
}

// ------------- gather aggregation: softmax-weighted sum per dst ------------
// block = 1 wave = 2 nodes x 32 lanes; parity b&1 selects head pair and its
// 6.4MB h-half -> per-XCD L2 working set halves under round-robin dispatch.
// lane li handles features 2li,2li+1 of the pair's 64-feature half.
__global__ __launch_bounds__(64) void aggregate(const unsigned* __restrict__ h0,
                                                const unsigned* __restrict__ h1,
                                                const __half2* __restrict__ w0,
                                                const __half2* __restrict__ w1,
                                                const float* __restrict__ a_s,
                                                const float* __restrict__ a_d,
                                                const int* __restrict__ row_ptr,
                                                const int* __restrict__ col,
                                                const float* __restrict__ bias,
                                                float* __restrict__ out,
                                                float* __restrict__ out2,
                                                int n, int do_relu) {
    const int b = blockIdx.x;
    const int p = b & 1;                    // head pair
    const unsigned* __restrict__ hp = p ? h1 : h0;
    const __half2* __restrict__ wp = p ? w1 : w0;
    const int t = threadIdx.x;
    const int g = t >> 5;                   // node within pair
    const int li = t & 31;
    const int node = (b >> 1) * 2 + g;
    if (node >= n) return;
    const int hd = p * 2 + (li >> 4);
    const bool hiH = (li >> 4) != 0;

    // self loop
    float e = a_s[node * NHEAD + hd] + a_d[node * NHEAD + hd];
    e = fmaxf(e, 0.2f * e);
    float den = __expf(e);
    float2 hv = bf2f(hp[(size_t)node * 32 + li]);
    float num0 = den * hv.x, num1 = den * hv.y;

    const int beg = row_ptr[node], end = row_ptr[node + 1];
    int j = beg;
    for (; j + 8 <= end; j += 8) {
        int s[8];
        #pragma unroll
        for (int u = 0; u < 8; u++) s[u] = col[j + u];
        unsigned v[8]; __half2 hw[8];
        #pragma unroll
        for (int u = 0; u < 8; u++) v[u] = hp[(size_t)s[u] * 32 + li];
        #pragma unroll
        for (int u = 0; u < 8; u++) hw[u] = wp[j + u];
        #pragma unroll
        for (int u = 0; u < 8; u++) {
            float wgt = hiH ? __high2float(hw[u]) : __low2float(hw[u]);
            den += wgt;
            float2 f = bf2f(v[u]);
            num0 += wgt * f.x;
            num1 += wgt * f.y;
        }
    }
    for (; j < end; j++) {
        int s = col[j];
        __half2 hw = wp[j];
        float wgt = hiH ? __high2float(hw) : __low2float(hw);
        den += wgt;
        float2 f = bf2f(hp[(size_t)s * 32 + li]);
        num0 += wgt * f.x;
        num1 += wgt * f.y;
    }
    float2 bv = ((const float2*)bias)[p * 32 + li];
    float rd = 1.0f / den;
    float o0 = num0 * rd + bv.x;
    float o1 = num1 * rd + bv.y;
    if (do_relu) { o0 = fmaxf(o0, 0.f); o1 = fmaxf(o1, 0.f); }
    ((float2*)out)[(size_t)node * 64 + p * 32 + li] = make_float2(o0, o1);
    if (out2) ((float2*)out2)[(size_t)node * 64 + p * 32 + li] = make_float2(o0, o1);
}

// ------------------------------- launcher ----------------------------------
extern "C" void kernel_launch(void* const* d_in, const int* in_sizes, int n_in,
                              void* d_out, int out_size, void* d_ws, size_t ws_size,
                              hipStream_t stream) {
    const float* x        = (const float*)d_in[0];
    const int*   edge     = (const int*)d_in[1];
    const float* W1       = (const float*)d_in[2];
    const float* att_s1   = (const float*)d_in[3];
    const float* att_d1   = (const float*)d_in[4];
    const float* b1       = (const float*)d_in[5];
    const float* W2       = (const float*)d_in[6];
    const float* att_s2   = (const float*)d_in[7];
    const float* att_d2   = (const float*)d_in[8];
    const float* b2       = (const float*)d_in[9];
    float* out = (float*)d_out;

    const int N = in_sizes[0] / FDIM;         // 50000
    const int E = in_sizes[1] / 2;            // 1600000
    const int* src = edge;
    const int* dst = edge + E;

    const int npb = (N + NB - 1) / NB;        // 98
    const unsigned long long magic = ((1ull << 40) / (unsigned long long)npb) + 1;

    char* w = (char*)d_ws;
    size_t off = 0;
    auto alloc = [&](size_t bytes) { void* p = w + off; off = (off + bytes + 255) & ~(size_t)255; return p; };
    int*   row_ptr = (int*)alloc((size_t)(N + 1) * 4);
    int*   col     = (int*)alloc((size_t)E * 4);
    int*   edst    = (int*)alloc((size_t)E * 4);
    __half2* w0    = (__half2*)alloc((size_t)E * 4);        // heads 0,1 fp16
    __half2* w1    = (__half2*)alloc((size_t)E * 4);        // heads 2,3 fp16
    int*   bcnt    = (int*)alloc((size_t)NB * 4);
    int*   bbase   = (int*)alloc((size_t)(NB + 1) * 4);
    int*   bcursor = (int*)alloc((size_t)NB * 4);
    unsigned short* h0 = (unsigned short*)alloc((size_t)N * 64 * 2);  // heads 0,1 bf16
    unsigned short* h1 = (unsigned short*)alloc((size_t)N * 64 * 2);  // heads 2,3 bf16
    float* hx      = (float*)alloc((size_t)N * FDIM * 4);   // layer-1 out; ebuf alias
    float* as1     = (float*)alloc((size_t)N * NHEAD * 4);
    float* ad1     = (float*)alloc((size_t)N * NHEAD * 4);
    float* as2     = (float*)alloc((size_t)N * NHEAD * 4);
    float* ad2     = (float*)alloc((size_t)N * NHEAD * 4);
    short* Bg1hi   = (short*)alloc((size_t)128 * 128 * 2);
    short* Bg1lo   = (short*)alloc((size_t)128 * 128 * 2);
    short* Bg2hi   = (short*)alloc((size_t)128 * 128 * 2);
    short* Bg2lo   = (short*)alloc((size_t)128 * 128 * 2);
    int2*  ebuf    = (int2*)hx;   // dead before aggregate-1 writes hx
    (void)ws_size;

    // ---- fused weight-prep + bucket histogram ----
    hipMemsetAsync(bcnt, 0, (size_t)NB * 4, stream);
    prep_hist<<<128 + 1024, 256, 0, stream>>>(W1, Bg1hi, Bg1lo, W2, Bg2hi, Bg2lo,
                                              dst, E, magic, bcnt);
    bucket_scan<<<1, 256, 0, stream>>>(bcnt, bbase, bcursor, row_ptr, N, E);
    partition<<<(E + 4095) / 4096, 256, 0, stream>>>(src, dst, E, magic, bcursor, ebuf);
    build_bucket<<<NB, 256, 0, stream>>>(ebuf, bbase, npb, N, row_ptr, col, edst);

    const int gblocks = (N + 63) / 64;
    const int eb = (E + 255) / 256;
    const int ablocks = ((N + 1) / 2) * 2;    // node pairs x 2 parities

    // ---- layer 1 ----
    gemm_mfma<<<gblocks, 256, 0, stream>>>(x, Bg1hi, Bg1lo, h0, h1,
                                           att_s1, att_d1, as1, ad1, N);
    edge_w<<<eb, 256, 0, stream>>>(col, edst, (const float4*)as1, (const float4*)ad1,
                                   E, w0, w1);
    aggregate<<<ablocks, 64, 0, stream>>>((const unsigned*)h0, (const unsigned*)h1,
                                          w0, w1, as1, ad1, row_ptr, col, b1,
                                          hx, nullptr, N, 1);

    // ---- layer 2 ----
    gemm_mfma<<<gblocks, 256, 0, stream>>>(hx, Bg2hi, Bg2lo, h0, h1,
                                           att_s2, att_d2, as2, ad2, N);
    edge_w<<<eb, 256, 0, stream>>>(col, edst, (const float4*)as2, (const float4*)ad2,
                                   E, w0, w1);
    aggregate<<<ablocks, 64, 0, stream>>>((const unsigned*)h0, (const unsigned*)h1,
                                          w0, w1, as2, ad2, row_ptr, col, b2,
                                          out, out + (size_t)N * FDIM, N, 0);
}